// Round 2
// baseline (483.341 us; speedup 1.0000x reference)
//
#include <hip/hip_runtime.h>
#include <stdint.h>

typedef unsigned short u16;
typedef __bf16 bf16_t;
typedef bf16_t bf16x8 __attribute__((ext_vector_type(8)));
typedef float f32x4 __attribute__((ext_vector_type(4)));

__device__ __forceinline__ u16 f2bf(float f) {
  union { float f; unsigned int u; } v; v.f = f;
  return (u16)((v.u + 0x7FFFu + ((v.u >> 16) & 1u)) >> 16);
}
__device__ __forceinline__ float bf2f(u16 b) {
  union { unsigned int u; float f; } v; v.u = ((unsigned int)b) << 16;
  return v.f;
}

#define MFMA16(a, b, c) __builtin_amdgcn_mfma_f32_16x16x32_bf16((a), (b), (c), 0, 0, 0)
#define GLL16(g, l) __builtin_amdgcn_global_load_lds( \
    (const __attribute__((address_space(1))) void*)(g), \
    (__attribute__((address_space(3))) void*)(l), 16, 0, 0)

#define SCALE 0.07216878364870323f  // 1/sqrt(3*64)

// ---------------- fp32 -> bf16 elementwise ----------------
__global__ void cvt_bf16(const float* __restrict__ in, u16* __restrict__ out, int n4) {
  int i = blockIdx.x * 256 + threadIdx.x;
  if (i >= n4) return;
  float4 v = ((const float4*)in)[i];
  ushort4 o;
  o.x = f2bf(v.x); o.y = f2bf(v.y); o.z = f2bf(v.z); o.w = f2bf(v.w);
  ((ushort4*)out)[i] = o;
}

// ---------------- 1024x1024 fp32 -> bf16 transpose (out[n][k] = in[k][n]) ----------------
__global__ void transp_bf16(const float* __restrict__ in, u16* __restrict__ out) {
  __shared__ float t[32][33];
  int tx = threadIdx.x & 31, ty = threadIdx.x >> 5;
  int x0 = blockIdx.x * 32, y0 = blockIdx.y * 32;
  #pragma unroll
  for (int i = ty; i < 32; i += 8)
    t[i][tx] = in[(size_t)(y0 + i) * 1024 + x0 + tx];
  __syncthreads();
  #pragma unroll
  for (int i = ty; i < 32; i += 8)
    out[(size_t)(x0 + i) * 1024 + y0 + tx] = f2bf(t[tx][i]);
}

// ---------------- bf16 GEMM: C[M,1024] = A[M,1024] * BT[1024,1024]^T + bias ----------------
// mode 0: out[(b*16+h)][s][d]   (q,k)     mode 1: out[(b*16+h)][d][s]   (v)
// mode 2: out[h][r][d]          (rel projections, M=1025)
__global__ void __launch_bounds__(256) gemm_bt(
    const u16* __restrict__ A, const u16* __restrict__ BT,
    const float* __restrict__ bias, u16* __restrict__ out,
    int M, int mode) {
  __shared__ __align__(16) u16 As[4096];
  __shared__ __align__(16) u16 Bs[4096];
  const int K = 1024;
  const int m0 = blockIdx.x * 128, n0 = blockIdx.y * 128;
  const int w = threadIdx.x >> 6, lane = threadIdx.x & 63;
  const int lj = lane & 15, lg = lane >> 4;
  const int wm = (w >> 1) * 64, wn = (w & 1) * 64;

  f32x4 acc[4][4] = {};

  const int chunk0 = w * 128 + lane;
  const int chunk1 = chunk0 + 64;
  int r0 = chunk0 >> 2, s0 = (chunk0 & 3) * 8;
  int r1 = chunk1 >> 2, s1 = (chunk1 & 3) * 8;
  int ar0 = m0 + r0; if (ar0 >= M) ar0 = M - 1;
  int ar1 = m0 + r1; if (ar1 >= M) ar1 = M - 1;
  const u16* ga0 = A + (size_t)ar0 * K + s0;
  const u16* ga1 = A + (size_t)ar1 * K + s1;
  const u16* gb0 = BT + (size_t)(n0 + r0) * K + s0;
  const u16* gb1 = BT + (size_t)(n0 + r1) * K + s1;
  u16* lA0 = As + (w * 2 + 0) * 512;
  u16* lA1 = As + (w * 2 + 1) * 512;
  u16* lB0 = Bs + (w * 2 + 0) * 512;
  u16* lB1 = Bs + (w * 2 + 1) * 512;

  for (int k0 = 0; k0 < K; k0 += 32) {
    GLL16(ga0 + k0, lA0);
    GLL16(ga1 + k0, lA1);
    GLL16(gb0 + k0, lB0);
    GLL16(gb1 + k0, lB1);
    __syncthreads();
    bf16x8 af[4], bf8[4];
    #pragma unroll
    for (int mf = 0; mf < 4; ++mf)
      af[mf] = *(const bf16x8*)(As + (wm + mf * 16 + lj) * 32 + lg * 8);
    #pragma unroll
    for (int nf = 0; nf < 4; ++nf)
      bf8[nf] = *(const bf16x8*)(Bs + (wn + nf * 16 + lj) * 32 + lg * 8);
    #pragma unroll
    for (int mf = 0; mf < 4; ++mf)
      #pragma unroll
      for (int nf = 0; nf < 4; ++nf)
        acc[mf][nf] = MFMA16(af[mf], bf8[nf], acc[mf][nf]);
    __syncthreads();
  }

  #pragma unroll
  for (int mf = 0; mf < 4; ++mf) {
    #pragma unroll
    for (int nf = 0; nf < 4; ++nf) {
      const int j = n0 + wn + nf * 16 + lj;
      const float bj = bias[j];
      #pragma unroll
      for (int r = 0; r < 4; ++r) {
        const int i = m0 + wm + mf * 16 + lg * 4 + r;
        if (i >= M) continue;
        const u16 val = f2bf(acc[mf][nf][r] + bj);
        if (mode == 0) {
          out[(size_t)(((i >> 10) << 4) + (j >> 6)) * 65536 + (size_t)(i & 1023) * 64 + (j & 63)] = val;
        } else if (mode == 1) {
          out[(size_t)(((i >> 10) << 4) + (j >> 6)) * 65536 + (size_t)(j & 63) * 1024 + (i & 1023)] = val;
        } else {
          out[(size_t)(j >> 6) * 65600 + (size_t)i * 64 + (j & 63)] = val;
        }
      }
    }
  }
}

// ---------------- fused disentangled attention ----------------
// grid: 1024 blocks = (b*16+n)*16 + i_tile ; block: 256 threads (4 waves)
// scores[i,j] = (q_i.k_j + q_i.relk[clip(i-j)+512] + k_j.relq[clip(j-i)+512]) * SCALE + mask[b,j]
// LDS = 80,640 B -> 2 blocks/CU. RK/RQ fragments read direct from global (L2-resident).
__global__ void __launch_bounds__(256, 2) attn_fused(
    const u16* __restrict__ qg, const u16* __restrict__ kg, const u16* __restrict__ vtg,
    const u16* __restrict__ rkg, const u16* __restrict__ rqg,
    const float* __restrict__ mask, float* __restrict__ out) {
  __shared__ __align__(16) u16 Qs[64][72];
  __shared__ __align__(16) u16 Ks[64][72];
  __shared__ __align__(16) u16 VTs[64][72];
  __shared__ __align__(16) u16 Ps[64][72];
  __shared__ __align__(16) u16 Ts[64][132];   // bf16 T, stride 264B -> conflict-free octets
  __shared__ __align__(16) u16 Us[64][132];

  // XCD swizzle: 1024 blocks, 8 XCDs -> 128 consecutive per XCD (same-head rel tables stay in one L2)
  const int bx = ((blockIdx.x & 7) << 7) | (blockIdx.x >> 3);
  const int it = bx & 15, bn = bx >> 4;
  const int b = bn >> 4, n = bn & 15;
  const int i0 = it * 64;
  const int tid = threadIdx.x, w = tid >> 6, lane = tid & 63;
  const int lj = lane & 15, lg = lane >> 4;

  const u16* qh = qg + (size_t)bn * 65536;
  const u16* kh = kg + (size_t)bn * 65536;
  const u16* vth = vtg + (size_t)bn * 65536;
  const u16* rkh = rkg + (size_t)n * 65600;
  const u16* rqh = rqg + (size_t)n * 65600;
  const float* mk = mask + (size_t)b * 1024;

  // stage Q tile once
  {
    int r = tid >> 2, c = (tid & 3) * 16;
    *(uint4*)(&Qs[r][c])     = *(const uint4*)(qh + (size_t)(i0 + r) * 64 + c);
    *(uint4*)(&Qs[r][c + 8]) = *(const uint4*)(qh + (size_t)(i0 + r) * 64 + c + 8);
  }

  float m_r[4], l_r[4];
  f32x4 accO[4] = {};
  #pragma unroll
  for (int r = 0; r < 4; ++r) { m_r[r] = -3e38f; l_r[r] = 0.f; }

  for (int jt = 0; jt < 16; ++jt) {
    const int j0 = jt * 64;
    __syncthreads();  // prev iter done reading Ks/VTs/Ts/Us
    {
      int r = tid >> 2, c = (tid & 3) * 16;
      *(uint4*)(&Ks[r][c])      = *(const uint4*)(kh + (size_t)(j0 + r) * 64 + c);
      *(uint4*)(&Ks[r][c + 8])  = *(const uint4*)(kh + (size_t)(j0 + r) * 64 + c + 8);
      *(uint4*)(&VTs[r][c])     = *(const uint4*)(vth + (size_t)r * 1024 + j0 + c);
      *(uint4*)(&VTs[r][c + 8]) = *(const uint4*)(vth + (size_t)r * 1024 + j0 + c + 8);
    }
    const int dd = i0 - j0 + 512;
    int w0 = dd - 63; w0 = w0 < 0 ? 0 : (w0 > 897 ? 897 : w0);
    const int ddq = j0 - i0 + 512;
    int w0q = ddq - 63; w0q = w0q < 0 ? 0 : (w0q > 897 ? 897 : w0q);
    __syncthreads();  // K/VT staged

    bf16x8 aq[2], ak[2];
    #pragma unroll
    for (int k2 = 0; k2 < 2; ++k2) {
      aq[k2] = *(const bf16x8*)(&Qs[w * 16 + lj][k2 * 32 + lg * 8]);
      ak[k2] = *(const bf16x8*)(&Ks[w * 16 + lj][k2 * 32 + lg * 8]);
    }
    // c2c: rows i in [w*16, w*16+16)
    f32x4 scc[4];
    #pragma unroll
    for (int jf = 0; jf < 4; ++jf) {
      scc[jf] = (f32x4){0.f, 0.f, 0.f, 0.f};
      #pragma unroll
      for (int k2 = 0; k2 < 2; ++k2) {
        bf16x8 bk8 = *(const bf16x8*)(&Ks[jf * 16 + lj][k2 * 32 + lg * 8]);
        scc[jf] = MFMA16(aq[k2], bk8, scc[jf]);
      }
    }
    // T[i,t] = q_i . relk[w0+t];  U[j,t] = k_j . relq[w0q+t] — B frags direct from global (L2)
    #pragma unroll
    for (int tf = 0; tf < 8; ++tf) {
      const u16* gk = rkh + (size_t)(w0 + tf * 16 + lj) * 64 + lg * 8;
      const u16* gq = rqh + (size_t)(w0q + tf * 16 + lj) * 64 + lg * 8;
      f32x4 t_ = {0.f, 0.f, 0.f, 0.f};
      f32x4 u_ = {0.f, 0.f, 0.f, 0.f};
      #pragma unroll
      for (int k2 = 0; k2 < 2; ++k2) {
        bf16x8 brk = *(const bf16x8*)(gk + k2 * 32);
        bf16x8 brq = *(const bf16x8*)(gq + k2 * 32);
        t_ = MFMA16(aq[k2], brk, t_);
        u_ = MFMA16(ak[k2], brq, u_);
      }
      #pragma unroll
      for (int r = 0; r < 4; ++r) {
        Ts[w * 16 + lg * 4 + r][tf * 16 + lj] = f2bf(t_[r]);
        Us[w * 16 + lg * 4 + r][tf * 16 + lj] = f2bf(u_[r]);
      }
    }
    __syncthreads();  // T/U visible cross-wave

    // assemble scores + online softmax
    float sc[4][4];
    float rmax[4] = {-3e38f, -3e38f, -3e38f, -3e38f};
    #pragma unroll
    for (int jf = 0; jf < 4; ++jf) {
      const int j_loc = jf * 16 + lj;
      const int j = j0 + j_loc;
      const float mj = mk[j];
      #pragma unroll
      for (int r = 0; r < 4; ++r) {
        const int i_loc = w * 16 + lg * 4 + r;
        const int i = i0 + i_loc;
        int x1 = i - j + 512; x1 = x1 < 0 ? 0 : (x1 > 1024 ? 1024 : x1);
        int x2 = j - i + 512; x2 = x2 < 0 ? 0 : (x2 > 1024 ? 1024 : x2);
        float s = (scc[jf][r] + bf2f(Ts[i_loc][x1 - w0]) + bf2f(Us[j_loc][x2 - w0q])) * SCALE + mj;
        sc[jf][r] = s;
        rmax[r] = fmaxf(rmax[r], s);
      }
    }
    #pragma unroll
    for (int off = 1; off < 16; off <<= 1)
      #pragma unroll
      for (int r = 0; r < 4; ++r)
        rmax[r] = fmaxf(rmax[r], __shfl_xor(rmax[r], off));
    float pfac[4], rsum[4];
    #pragma unroll
    for (int r = 0; r < 4; ++r) {
      float mnew = fmaxf(m_r[r], rmax[r]);
      pfac[r] = __expf(m_r[r] - mnew);
      m_r[r] = mnew;
      rsum[r] = 0.f;
    }
    #pragma unroll
    for (int jf = 0; jf < 4; ++jf)
      #pragma unroll
      for (int r = 0; r < 4; ++r) {
        float p = __expf(sc[jf][r] - m_r[r]);
        rsum[r] += p;
        Ps[w * 16 + lg * 4 + r][jf * 16 + lj] = f2bf(p);
      }
    #pragma unroll
    for (int off = 1; off < 16; off <<= 1)
      #pragma unroll
      for (int r = 0; r < 4; ++r)
        rsum[r] += __shfl_xor(rsum[r], off);
    #pragma unroll
    for (int r = 0; r < 4; ++r)
      l_r[r] = l_r[r] * pfac[r] + rsum[r];
    #pragma unroll
    for (int d = 0; d < 4; ++d)
      #pragma unroll
      for (int r = 0; r < 4; ++r)
        accO[d][r] *= pfac[r];
    // PV: O[i,d] += P[i,j] * V[j,d]  (P rows own wave -> intra-wave LDS dependency only)
    #pragma unroll
    for (int jk = 0; jk < 2; ++jk) {
      bf16x8 ap = *(const bf16x8*)(&Ps[w * 16 + lj][jk * 32 + lg * 8]);
      #pragma unroll
      for (int d = 0; d < 4; ++d) {
        bf16x8 bv8 = *(const bf16x8*)(&VTs[d * 16 + lj][jk * 32 + lg * 8]);
        accO[d] = MFMA16(ap, bv8, accO[d]);
      }
    }
  }

  #pragma unroll
  for (int r = 0; r < 4; ++r) {
    const float inv = 1.f / l_r[r];
    const int i = i0 + w * 16 + lg * 4 + r;
    #pragma unroll
    for (int d = 0; d < 4; ++d)
      out[((size_t)b * 1024 + i) * 1024 + n * 64 + d * 16 + lj] = accO[d][r] * inv;
  }
}

extern "C" void kernel_launch(void* const* d_in, const int* in_sizes, int n_in,
                              void* d_out, int out_size, void* d_ws, size_t ws_size,
                              hipStream_t stream) {
  const float* hs   = (const float*)d_in[0];
  const float* mask = (const float*)d_in[1];
  const float* rel  = (const float*)d_in[2];
  const float* Wq   = (const float*)d_in[3];
  const float* bq   = (const float*)d_in[4];
  const float* Wk   = (const float*)d_in[5];
  const float* bk   = (const float*)d_in[6];
  const float* Wv   = (const float*)d_in[7];
  const float* bv   = (const float*)d_in[8];
  const float* Wpk  = (const float*)d_in[9];
  const float* bpk  = (const float*)d_in[10];
  const float* Wpq  = (const float*)d_in[11];
  const float* bpq  = (const float*)d_in[12];
  float* outp = (float*)d_out;

  u16* p = (u16*)d_ws;
  u16* hsb  = p; p += (size_t)4096 * 1024;
  u16* relb = p; p += (size_t)1025 * 1024;
  u16* WqT  = p; p += (size_t)1024 * 1024;
  u16* WkT  = p; p += (size_t)1024 * 1024;
  u16* WvT  = p; p += (size_t)1024 * 1024;
  u16* WpkT = p; p += (size_t)1024 * 1024;
  u16* WpqT = p; p += (size_t)1024 * 1024;
  u16* qws  = p; p += (size_t)4096 * 1024;
  u16* kws  = p; p += (size_t)4096 * 1024;
  u16* vws  = p; p += (size_t)4096 * 1024;
  u16* rkws = p; p += (size_t)16 * 1025 * 64;
  u16* rqws = p; p += (size_t)16 * 1025 * 64;
  if ((size_t)((char*)p - (char*)d_ws) > ws_size) return;  // ws too small: bail

  cvt_bf16<<<4096, 256, 0, stream>>>(hs, hsb, 1048576);
  cvt_bf16<<<1025, 256, 0, stream>>>(rel, relb, 262400);
  transp_bf16<<<dim3(32, 32), 256, 0, stream>>>(Wq,  WqT);
  transp_bf16<<<dim3(32, 32), 256, 0, stream>>>(Wk,  WkT);
  transp_bf16<<<dim3(32, 32), 256, 0, stream>>>(Wv,  WvT);
  transp_bf16<<<dim3(32, 32), 256, 0, stream>>>(Wpk, WpkT);
  transp_bf16<<<dim3(32, 32), 256, 0, stream>>>(Wpq, WpqT);

  gemm_bt<<<dim3(32, 8), 256, 0, stream>>>(hsb, WqT, bq, qws, 4096, 0);
  gemm_bt<<<dim3(32, 8), 256, 0, stream>>>(hsb, WkT, bk, kws, 4096, 0);
  gemm_bt<<<dim3(32, 8), 256, 0, stream>>>(hsb, WvT, bv, vws, 4096, 1);
  gemm_bt<<<dim3(9, 8),  256, 0, stream>>>(relb, WpkT, bpk, rkws, 1025, 2);
  gemm_bt<<<dim3(9, 8),  256, 0, stream>>>(relb, WpqT, bpq, rqws, 1025, 2);

  attn_fused<<<1024, 256, 0, stream>>>(qws, kws, vws, rkws, rqws, mask, outp);
}

// Round 4
// 309.255 us; speedup vs baseline: 1.5629x; 1.5629x over previous
//
#include <hip/hip_runtime.h>
#include <stdint.h>

typedef unsigned short u16;
typedef __bf16 bf16_t;
typedef bf16_t bf16x8 __attribute__((ext_vector_type(8)));
typedef float f32x4 __attribute__((ext_vector_type(4)));

__device__ __forceinline__ u16 f2bf(float f) {
  union { float f; unsigned int u; } v; v.f = f;
  return (u16)((v.u + 0x7FFFu + ((v.u >> 16) & 1u)) >> 16);
}
__device__ __forceinline__ float bf2f(u16 b) {
  union { unsigned int u; float f; } v; v.u = ((unsigned int)b) << 16;
  return v.f;
}

#define MFMA16(a, b, c) __builtin_amdgcn_mfma_f32_16x16x32_bf16((a), (b), (c), 0, 0, 0)
#define GLL16(g, l) __builtin_amdgcn_global_load_lds( \
    (const __attribute__((address_space(1))) void*)(g), \
    (__attribute__((address_space(3))) void*)(l), 16, 0, 0)

// granule-XOR swizzle: permutes 8-u16 granules within a 64/128-col row; same
// formula on write and read -> bijective & self-consistent.
#define SWZ(row, col) ((col) ^ (((row) & 7) << 3))

#define SCALE 0.07216878364870323f  // 1/sqrt(3*64)

// ---------------- fp32 -> bf16 elementwise ----------------
__global__ void cvt_bf16(const float* __restrict__ in, u16* __restrict__ out, int n4) {
  int i = blockIdx.x * 256 + threadIdx.x;
  if (i >= n4) return;
  float4 v = ((const float4*)in)[i];
  ushort4 o;
  o.x = f2bf(v.x); o.y = f2bf(v.y); o.z = f2bf(v.z); o.w = f2bf(v.w);
  ((ushort4*)out)[i] = o;
}

// ---------------- 5x fused 1024x1024 fp32 -> bf16 transpose ----------------
__global__ void transp5_bf16(const float* __restrict__ i0, const float* __restrict__ i1,
                             const float* __restrict__ i2, const float* __restrict__ i3,
                             const float* __restrict__ i4,
                             u16* __restrict__ o0, u16* __restrict__ o1,
                             u16* __restrict__ o2, u16* __restrict__ o3,
                             u16* __restrict__ o4) {
  __shared__ float t[32][33];
  const float* in;
  u16* out;
  switch (blockIdx.z) {
    case 0: in = i0; out = o0; break;
    case 1: in = i1; out = o1; break;
    case 2: in = i2; out = o2; break;
    case 3: in = i3; out = o3; break;
    default: in = i4; out = o4; break;
  }
  int tx = threadIdx.x & 31, ty = threadIdx.x >> 5;
  int x0 = blockIdx.x * 32, y0 = blockIdx.y * 32;
  #pragma unroll
  for (int i = ty; i < 32; i += 8)
    t[i][tx] = in[(size_t)(y0 + i) * 1024 + x0 + tx];
  __syncthreads();
  #pragma unroll
  for (int i = ty; i < 32; i += 8)
    out[(size_t)(x0 + i) * 1024 + y0 + tx] = f2bf(t[tx][i]);
}

// ---------------- fused multi-matrix bf16 GEMM ----------------
// C[M,1024] = A[M,1024] * BT_mat[1024,1024]^T + bias_mat, mat = blockIdx.y>>3
// rel==0 (qkv, grid 32x24): mat 0,1 -> out[(b*16+h)][s][d]; mat 2 -> out[(b*16+h)][d][s]
// rel==1 (grid 9x16):       mat 0,1 -> out + mat*1049600, layout [h][r][d]
__global__ void __launch_bounds__(256) gemm_multi(
    const u16* __restrict__ A, const u16* __restrict__ BT,
    const float* __restrict__ b0, const float* __restrict__ b1, const float* __restrict__ b2,
    u16* __restrict__ out, int M, int rel) {
  __shared__ __align__(16) u16 As[4096];
  __shared__ __align__(16) u16 Bs[4096];
  const int K = 1024;
  const int mat = blockIdx.y >> 3;
  const u16* BTm = BT + (size_t)mat * 1048576;
  const float* bias = (mat == 0) ? b0 : ((mat == 1) ? b1 : b2);
  const int m0 = blockIdx.x * 128, n0 = (blockIdx.y & 7) * 128;
  const int w = threadIdx.x >> 6, lane = threadIdx.x & 63;
  const int lj = lane & 15, lg = lane >> 4;
  const int wm = (w >> 1) * 64, wn = (w & 1) * 64;

  f32x4 acc[4][4] = {};

  const int chunk0 = w * 128 + lane;
  const int chunk1 = chunk0 + 64;
  int r0 = chunk0 >> 2, s0 = (chunk0 & 3) * 8;
  int r1 = chunk1 >> 2, s1 = (chunk1 & 3) * 8;
  int ar0 = m0 + r0; if (ar0 >= M) ar0 = M - 1;
  int ar1 = m0 + r1; if (ar1 >= M) ar1 = M - 1;
  const u16* ga0 = A + (size_t)ar0 * K + s0;
  const u16* ga1 = A + (size_t)ar1 * K + s1;
  const u16* gb0 = BTm + (size_t)(n0 + r0) * K + s0;
  const u16* gb1 = BTm + (size_t)(n0 + r1) * K + s1;
  u16* lA0 = As + (w * 2 + 0) * 512;
  u16* lA1 = As + (w * 2 + 1) * 512;
  u16* lB0 = Bs + (w * 2 + 0) * 512;
  u16* lB1 = Bs + (w * 2 + 1) * 512;

  for (int k0 = 0; k0 < K; k0 += 32) {
    GLL16(ga0 + k0, lA0);
    GLL16(ga1 + k0, lA1);
    GLL16(gb0 + k0, lB0);
    GLL16(gb1 + k0, lB1);
    __syncthreads();
    bf16x8 af[4], bf8[4];
    #pragma unroll
    for (int mf = 0; mf < 4; ++mf)
      af[mf] = *(const bf16x8*)(As + (wm + mf * 16 + lj) * 32 + lg * 8);
    #pragma unroll
    for (int nf = 0; nf < 4; ++nf)
      bf8[nf] = *(const bf16x8*)(Bs + (wn + nf * 16 + lj) * 32 + lg * 8);
    #pragma unroll
    for (int mf = 0; mf < 4; ++mf)
      #pragma unroll
      for (int nf = 0; nf < 4; ++nf)
        acc[mf][nf] = MFMA16(af[mf], bf8[nf], acc[mf][nf]);
    __syncthreads();
  }

  #pragma unroll
  for (int mf = 0; mf < 4; ++mf) {
    #pragma unroll
    for (int nf = 0; nf < 4; ++nf) {
      const int j = n0 + wn + nf * 16 + lj;
      const float bj = bias[j];
      #pragma unroll
      for (int r = 0; r < 4; ++r) {
        const int i = m0 + wm + mf * 16 + lg * 4 + r;
        if (i >= M) continue;
        const u16 val = f2bf(acc[mf][nf][r] + bj);
        if (rel) {
          out[(size_t)mat * 1049600 + (size_t)(j >> 6) * 65600 + (size_t)i * 64 + (j & 63)] = val;
        } else if (mat < 2) {
          out[(size_t)mat * 4194304 +
              (size_t)(((i >> 10) << 4) + (j >> 6)) * 65536 + (size_t)(i & 1023) * 64 + (j & 63)] = val;
        } else {
          out[(size_t)2 * 4194304 +
              (size_t)(((i >> 10) << 4) + (j >> 6)) * 65536 + (size_t)(j & 63) * 1024 + (i & 1023)] = val;
        }
      }
    }
  }
}

// ---------------- fused disentangled attention ----------------
// grid: 1024 blocks = (b*16+n)*16 + i_tile ; block: 256 threads (4 waves)
// scores[i,j] = (q_i.k_j + q_i.relk[clip(i-j)+512] + k_j.relq[clip(j-i)+512]) * SCALE + mask[b,j]
// LDS = 81,920 B exactly -> 2 blocks/CU. Q + V tiles in registers; NO buffer aliasing.
// All tiles unpadded with granule-XOR swizzle (SWZ) for bank spread.
__global__ void __launch_bounds__(256, 2) attn_fused(
    const u16* __restrict__ qg, const u16* __restrict__ kg, const u16* __restrict__ vtg,
    const u16* __restrict__ rkg, const u16* __restrict__ rqg,
    const float* __restrict__ mask, float* __restrict__ out) {
  __shared__ __align__(16) u16 Ks[64][64];     //  8192
  __shared__ __align__(16) u16 Ps[64][64];     //  8192
  __shared__ __align__(16) u16 RKs[128][64];   // 16384
  __shared__ __align__(16) u16 RQs[128][64];   // 16384
  __shared__ __align__(16) u16 Ts[64][128];    // 16384
  __shared__ __align__(16) u16 Us[64][128];    // 16384

  // XCD swizzle: 8 XCDs, 128 consecutive blocks each -> same-head rel tables stay in one L2
  const int bx = ((blockIdx.x & 7) << 7) | (blockIdx.x >> 3);
  const int it = bx & 15, bn = bx >> 4;
  const int b = bn >> 4, n = bn & 15;
  const int i0 = it * 64;
  const int tid = threadIdx.x, w = tid >> 6, lane = tid & 63;
  const int lj = lane & 15, lg = lane >> 4;

  const u16* qh = qg + (size_t)bn * 65536;
  const u16* kh = kg + (size_t)bn * 65536;
  const u16* vth = vtg + (size_t)bn * 65536;
  const u16* rkh = rkg + (size_t)n * 65600;
  const u16* rqh = rqg + (size_t)n * 65600;
  const float* mk = mask + (size_t)b * 1024;

  // Q fragment -> registers (wave-private rows, constant over jt)
  bf16x8 aq[2];
  #pragma unroll
  for (int k2 = 0; k2 < 2; ++k2)
    aq[k2] = *(const bf16x8*)(qh + (size_t)(i0 + w * 16 + lj) * 64 + k2 * 32 + lg * 8);

  float m_r[4], l_r[4];
  f32x4 accO[4] = {};
  #pragma unroll
  for (int r = 0; r < 4; ++r) { m_r[r] = -3e38f; l_r[r] = 0.f; }

  for (int jt = 0; jt < 16; ++jt) {
    const int j0 = jt * 64;
    __syncthreads();  // prev iter done reading Ks/RKs/RQs/Ts/Us/Ps
    {
      int r = tid >> 2, c = (tid & 3) * 16, sw = (r & 7) << 3;
      *(uint4*)(&Ks[r][c ^ sw])       = *(const uint4*)(kh + (size_t)(j0 + r) * 64 + c);
      *(uint4*)(&Ks[r][(c + 8) ^ sw]) = *(const uint4*)(kh + (size_t)(j0 + r) * 64 + c + 8);
    }
    const int dd = i0 - j0 + 512;
    int w0 = dd - 63; w0 = w0 < 0 ? 0 : (w0 > 897 ? 897 : w0);
    const int ddq = j0 - i0 + 512;
    int w0q = ddq - 63; w0q = w0q < 0 ? 0 : (w0q > 897 ? 897 : w0q);
    {
      int r = tid >> 1, c = (tid & 1) * 32, sw = (r & 7) << 3;
      const u16* srk = rkh + (size_t)(w0 + r) * 64 + c;
      *(uint4*)(&RKs[r][(c +  0) ^ sw]) = *(const uint4*)(srk);
      *(uint4*)(&RKs[r][(c +  8) ^ sw]) = *(const uint4*)(srk + 8);
      *(uint4*)(&RKs[r][(c + 16) ^ sw]) = *(const uint4*)(srk + 16);
      *(uint4*)(&RKs[r][(c + 24) ^ sw]) = *(const uint4*)(srk + 24);
      const u16* srq = rqh + (size_t)(w0q + r) * 64 + c;
      *(uint4*)(&RQs[r][(c +  0) ^ sw]) = *(const uint4*)(srq);
      *(uint4*)(&RQs[r][(c +  8) ^ sw]) = *(const uint4*)(srq + 8);
      *(uint4*)(&RQs[r][(c + 16) ^ sw]) = *(const uint4*)(srq + 16);
      *(uint4*)(&RQs[r][(c + 24) ^ sw]) = *(const uint4*)(srq + 24);
    }
    __syncthreads();  // staging visible

    bf16x8 ak[2];
    #pragma unroll
    for (int k2 = 0; k2 < 2; ++k2) {
      const int kr = w * 16 + lj;
      ak[k2] = *(const bf16x8*)(&Ks[kr][SWZ(kr, k2 * 32 + lg * 8)]);
    }
    // c2c: rows i in [w*16, w*16+16)
    f32x4 scc[4];
    #pragma unroll
    for (int jf = 0; jf < 4; ++jf) {
      scc[jf] = (f32x4){0.f, 0.f, 0.f, 0.f};
      #pragma unroll
      for (int k2 = 0; k2 < 2; ++k2) {
        const int kr = jf * 16 + lj;
        bf16x8 bk8 = *(const bf16x8*)(&Ks[kr][SWZ(kr, k2 * 32 + lg * 8)]);
        scc[jf] = MFMA16(aq[k2], bk8, scc[jf]);
      }
    }
    // T[i,t] = q_i . relk[w0+t] (wave-private rows); U[j,t] = k_j . relq[w0q+t]
    #pragma unroll
    for (int tf = 0; tf < 8; ++tf) {
      f32x4 t_ = {0.f, 0.f, 0.f, 0.f};
      f32x4 u_ = {0.f, 0.f, 0.f, 0.f};
      #pragma unroll
      for (int k2 = 0; k2 < 2; ++k2) {
        const int rr = tf * 16 + lj;
        bf16x8 brk = *(const bf16x8*)(&RKs[rr][SWZ(rr, k2 * 32 + lg * 8)]);
        bf16x8 brq = *(const bf16x8*)(&RQs[rr][SWZ(rr, k2 * 32 + lg * 8)]);
        t_ = MFMA16(aq[k2], brk, t_);
        u_ = MFMA16(ak[k2], brq, u_);
      }
      #pragma unroll
      for (int r = 0; r < 4; ++r) {
        const int tr = w * 16 + lg * 4 + r;
        Ts[tr][SWZ(tr, tf * 16 + lj)] = f2bf(t_[r]);
        Us[tr][SWZ(tr, tf * 16 + lj)] = f2bf(u_[r]);
      }
    }
    __syncthreads();  // T/U visible cross-wave

    // V tile -> registers NOW: L2 latency hides under softmax VALU work below
    bf16x8 vreg[8];
    #pragma unroll
    for (int jk = 0; jk < 2; ++jk)
      #pragma unroll
      for (int d = 0; d < 4; ++d)
        vreg[jk * 4 + d] = *(const bf16x8*)(vth + (size_t)(d * 16 + lj) * 1024 + j0 + jk * 32 + lg * 8);

    // assemble scores + online softmax
    float sc[4][4];
    float rmax[4] = {-3e38f, -3e38f, -3e38f, -3e38f};
    #pragma unroll
    for (int jf = 0; jf < 4; ++jf) {
      const int j_loc = jf * 16 + lj;
      const int j = j0 + j_loc;
      const float mj = mk[j];
      #pragma unroll
      for (int r = 0; r < 4; ++r) {
        const int i_loc = w * 16 + lg * 4 + r;
        const int i = i0 + i_loc;
        int x1 = i - j + 512; x1 = x1 < 0 ? 0 : (x1 > 1024 ? 1024 : x1);
        int x2 = j - i + 512; x2 = x2 < 0 ? 0 : (x2 > 1024 ? 1024 : x2);
        float s = (scc[jf][r] + bf2f(Ts[i_loc][SWZ(i_loc, x1 - w0)])
                              + bf2f(Us[j_loc][SWZ(j_loc, x2 - w0q)])) * SCALE + mj;
        sc[jf][r] = s;
        rmax[r] = fmaxf(rmax[r], s);
      }
    }
    #pragma unroll
    for (int off = 1; off < 16; off <<= 1)
      #pragma unroll
      for (int r = 0; r < 4; ++r)
        rmax[r] = fmaxf(rmax[r], __shfl_xor(rmax[r], off));
    float pfac[4], rsum[4];
    #pragma unroll
    for (int r = 0; r < 4; ++r) {
      float mnew = fmaxf(m_r[r], rmax[r]);
      pfac[r] = __expf(m_r[r] - mnew);
      m_r[r] = mnew;
      rsum[r] = 0.f;
    }
    #pragma unroll
    for (int jf = 0; jf < 4; ++jf)
      #pragma unroll
      for (int r = 0; r < 4; ++r) {
        float p = __expf(sc[jf][r] - m_r[r]);
        rsum[r] += p;
        const int pr = w * 16 + lg * 4 + r;
        Ps[pr][SWZ(pr, jf * 16 + lj)] = f2bf(p);
      }
    #pragma unroll
    for (int off = 1; off < 16; off <<= 1)
      #pragma unroll
      for (int r = 0; r < 4; ++r)
        rsum[r] += __shfl_xor(rsum[r], off);
    #pragma unroll
    for (int r = 0; r < 4; ++r)
      l_r[r] = l_r[r] * pfac[r] + rsum[r];
    #pragma unroll
    for (int d = 0; d < 4; ++d)
      #pragma unroll
      for (int r = 0; r < 4; ++r)
        accO[d][r] *= pfac[r];
    // PV: O[i,d] += P[i,j] * V[j,d]  (P rows wave-private; V from registers)
    #pragma unroll
    for (int jk = 0; jk < 2; ++jk) {
      const int pr = w * 16 + lj;
      bf16x8 ap = *(const bf16x8*)(&Ps[pr][SWZ(pr, jk * 32 + lg * 8)]);
      #pragma unroll
      for (int d = 0; d < 4; ++d)
        accO[d] = MFMA16(ap, vreg[jk * 4 + d], accO[d]);
    }
  }

  #pragma unroll
  for (int r = 0; r < 4; ++r) {
    const float inv = 1.f / l_r[r];
    const int i = i0 + w * 16 + lg * 4 + r;
    #pragma unroll
    for (int d = 0; d < 4; ++d)
      out[((size_t)b * 1024 + i) * 1024 + n * 64 + d * 16 + lj] = accO[d][r] * inv;
  }
}

extern "C" void kernel_launch(void* const* d_in, const int* in_sizes, int n_in,
                              void* d_out, int out_size, void* d_ws, size_t ws_size,
                              hipStream_t stream) {
  const float* hs   = (const float*)d_in[0];
  const float* mask = (const float*)d_in[1];
  const float* rel  = (const float*)d_in[2];
  const float* Wq   = (const float*)d_in[3];
  const float* bq   = (const float*)d_in[4];
  const float* Wk   = (const float*)d_in[5];
  const float* bk   = (const float*)d_in[6];
  const float* Wv   = (const float*)d_in[7];
  const float* bv   = (const float*)d_in[8];
  const float* Wpk  = (const float*)d_in[9];
  const float* bpk  = (const float*)d_in[10];
  const float* Wpq  = (const float*)d_in[11];
  const float* bpq  = (const float*)d_in[12];
  float* outp = (float*)d_out;

  u16* p = (u16*)d_ws;
  u16* hsb  = p; p += (size_t)4096 * 1024;
  u16* relb = p; p += (size_t)1025 * 1024;
  u16* WqT  = p; p += (size_t)1024 * 1024;   // WqT/WkT/WvT consecutive
  u16* WkT  = p; p += (size_t)1024 * 1024;
  u16* WvT  = p; p += (size_t)1024 * 1024;
  u16* WpkT = p; p += (size_t)1024 * 1024;   // WpkT/WpqT consecutive
  u16* WpqT = p; p += (size_t)1024 * 1024;
  u16* qws  = p; p += (size_t)4096 * 1024;   // q/k/v consecutive
  u16* kws  = p; p += (size_t)4096 * 1024;
  u16* vws  = p; p += (size_t)4096 * 1024;
  u16* rkws = p; p += (size_t)16 * 1025 * 64;  // rk/rq consecutive
  u16* rqws = p; p += (size_t)16 * 1025 * 64;
  if ((size_t)((char*)p - (char*)d_ws) > ws_size) return;  // ws too small: bail
  (void)kws; (void)rqws;

  cvt_bf16<<<4096, 256, 0, stream>>>(hs, hsb, 1048576);
  cvt_bf16<<<1025, 256, 0, stream>>>(rel, relb, 262400);
  transp5_bf16<<<dim3(32, 32, 5), 256, 0, stream>>>(Wq, Wk, Wv, Wpk, Wpq,
                                                    WqT, WkT, WvT, WpkT, WpqT);

  gemm_multi<<<dim3(32, 24), 256, 0, stream>>>(hsb, WqT, bq, bk, bv, qws, 4096, 0);
  gemm_multi<<<dim3(9, 16),  256, 0, stream>>>(relb, WpkT, bpk, bpq, bpq, rkws, 1025, 1);

  attn_fused<<<1024, 256, 0, stream>>>(qws, kws, vws, rkws, rqws, mask, outp);
}

// Round 5
// 229.272 us; speedup vs baseline: 2.1082x; 1.3489x over previous
//
#include <hip/hip_runtime.h>
#include <stdint.h>

typedef unsigned short u16;
typedef __bf16 bf16_t;
typedef bf16_t bf16x8 __attribute__((ext_vector_type(8)));
typedef float f32x4 __attribute__((ext_vector_type(4)));

__device__ __forceinline__ u16 f2bf(float f) {
  union { float f; unsigned int u; } v; v.f = f;
  return (u16)((v.u + 0x7FFFu + ((v.u >> 16) & 1u)) >> 16);
}
__device__ __forceinline__ float bf2f(u16 b) {
  union { unsigned int u; float f; } v; v.u = ((unsigned int)b) << 16;
  return v.f;
}

#define MFMA16(a, b, c) __builtin_amdgcn_mfma_f32_16x16x32_bf16((a), (b), (c), 0, 0, 0)
#define GLL16(g, l) __builtin_amdgcn_global_load_lds( \
    (const __attribute__((address_space(1))) void*)(g), \
    (__attribute__((address_space(3))) void*)(l), 16, 0, 0)

// granule-XOR swizzle: permutes 8-u16 granules within a row; same formula on
// write and read -> bijective & self-consistent.
#define SWZ(row, col) ((col) ^ (((row) & 7) << 3))

#define SCALE 0.07216878364870323f  // 1/sqrt(3*64)

// ---------------- fp32 -> bf16 elementwise ----------------
__global__ void cvt_bf16(const float* __restrict__ in, u16* __restrict__ out, int n4) {
  int i = blockIdx.x * 256 + threadIdx.x;
  if (i >= n4) return;
  float4 v = ((const float4*)in)[i];
  ushort4 o;
  o.x = f2bf(v.x); o.y = f2bf(v.y); o.z = f2bf(v.z); o.w = f2bf(v.w);
  ((ushort4*)out)[i] = o;
}

// ---------------- 5x fused 1024x1024 fp32 -> bf16 transpose ----------------
__global__ void transp5_bf16(const float* __restrict__ i0, const float* __restrict__ i1,
                             const float* __restrict__ i2, const float* __restrict__ i3,
                             const float* __restrict__ i4,
                             u16* __restrict__ o0, u16* __restrict__ o1,
                             u16* __restrict__ o2, u16* __restrict__ o3,
                             u16* __restrict__ o4) {
  __shared__ float t[32][33];
  const float* in;
  u16* out;
  switch (blockIdx.z) {
    case 0: in = i0; out = o0; break;
    case 1: in = i1; out = o1; break;
    case 2: in = i2; out = o2; break;
    case 3: in = i3; out = o3; break;
    default: in = i4; out = o4; break;
  }
  int tx = threadIdx.x & 31, ty = threadIdx.x >> 5;
  int x0 = blockIdx.x * 32, y0 = blockIdx.y * 32;
  #pragma unroll
  for (int i = ty; i < 32; i += 8)
    t[i][tx] = in[(size_t)(y0 + i) * 1024 + x0 + tx];
  __syncthreads();
  #pragma unroll
  for (int i = ty; i < 32; i += 8)
    out[(size_t)(x0 + i) * 1024 + y0 + tx] = f2bf(t[tx][i]);
}

// ---------------- fused multi-matrix bf16 GEMM ----------------
// C[M,1024] = A[M,1024] * BT_mat[1024,1024]^T + bias_mat, mat = blockIdx.y>>3
// rel==0 (qkv, grid 32x24): mat 0,1 -> out[(b*16+h)][s][d]; mat 2 -> out[(b*16+h)][d][s]
// rel==1 (grid 9x16):       mat 0,1 -> out + mat*1049600, layout [h][r][d]
__global__ void __launch_bounds__(256) gemm_multi(
    const u16* __restrict__ A, const u16* __restrict__ BT,
    const float* __restrict__ b0, const float* __restrict__ b1, const float* __restrict__ b2,
    u16* __restrict__ out, int M, int rel) {
  __shared__ __align__(16) u16 As[4096];
  __shared__ __align__(16) u16 Bs[4096];
  const int K = 1024;
  const int mat = blockIdx.y >> 3;
  const u16* BTm = BT + (size_t)mat * 1048576;
  const float* bias = (mat == 0) ? b0 : ((mat == 1) ? b1 : b2);
  const int m0 = blockIdx.x * 128, n0 = (blockIdx.y & 7) * 128;
  const int w = threadIdx.x >> 6, lane = threadIdx.x & 63;
  const int lj = lane & 15, lg = lane >> 4;
  const int wm = (w >> 1) * 64, wn = (w & 1) * 64;

  f32x4 acc[4][4] = {};

  const int chunk0 = w * 128 + lane;
  const int chunk1 = chunk0 + 64;
  int r0 = chunk0 >> 2, s0 = (chunk0 & 3) * 8;
  int r1 = chunk1 >> 2, s1 = (chunk1 & 3) * 8;
  int ar0 = m0 + r0; if (ar0 >= M) ar0 = M - 1;
  int ar1 = m0 + r1; if (ar1 >= M) ar1 = M - 1;
  const u16* ga0 = A + (size_t)ar0 * K + s0;
  const u16* ga1 = A + (size_t)ar1 * K + s1;
  const u16* gb0 = BTm + (size_t)(n0 + r0) * K + s0;
  const u16* gb1 = BTm + (size_t)(n0 + r1) * K + s1;
  u16* lA0 = As + (w * 2 + 0) * 512;
  u16* lA1 = As + (w * 2 + 1) * 512;
  u16* lB0 = Bs + (w * 2 + 0) * 512;
  u16* lB1 = Bs + (w * 2 + 1) * 512;

  for (int k0 = 0; k0 < K; k0 += 32) {
    GLL16(ga0 + k0, lA0);
    GLL16(ga1 + k0, lA1);
    GLL16(gb0 + k0, lB0);
    GLL16(gb1 + k0, lB1);
    __syncthreads();
    bf16x8 af[4], bf8[4];
    #pragma unroll
    for (int mf = 0; mf < 4; ++mf)
      af[mf] = *(const bf16x8*)(As + (wm + mf * 16 + lj) * 32 + lg * 8);
    #pragma unroll
    for (int nf = 0; nf < 4; ++nf)
      bf8[nf] = *(const bf16x8*)(Bs + (wn + nf * 16 + lj) * 32 + lg * 8);
    #pragma unroll
    for (int mf = 0; mf < 4; ++mf)
      #pragma unroll
      for (int nf = 0; nf < 4; ++nf)
        acc[mf][nf] = MFMA16(af[mf], bf8[nf], acc[mf][nf]);
    __syncthreads();
  }

  #pragma unroll
  for (int mf = 0; mf < 4; ++mf) {
    #pragma unroll
    for (int nf = 0; nf < 4; ++nf) {
      const int j = n0 + wn + nf * 16 + lj;
      const float bj = bias[j];
      #pragma unroll
      for (int r = 0; r < 4; ++r) {
        const int i = m0 + wm + mf * 16 + lg * 4 + r;
        if (i >= M) continue;
        const u16 val = f2bf(acc[mf][nf][r] + bj);
        if (rel) {
          out[(size_t)mat * 1049600 + (size_t)(j >> 6) * 65600 + (size_t)i * 64 + (j & 63)] = val;
        } else if (mat < 2) {
          out[(size_t)mat * 4194304 +
              (size_t)(((i >> 10) << 4) + (j >> 6)) * 65536 + (size_t)(i & 1023) * 64 + (j & 63)] = val;
        } else {
          out[(size_t)2 * 4194304 +
              (size_t)(((i >> 10) << 4) + (j >> 6)) * 65536 + (size_t)(j & 63) * 1024 + (i & 1023)] = val;
        }
      }
    }
  }
}

// ---------------- fused disentangled attention ----------------
// grid: 1024 blocks = (b*16+n)*16 + i_tile ; block: 256 threads (4 waves)
// scores[i,j] = (q_i.k_j + q_i.relk[clip(i-j)+512] + k_j.relq[clip(j-i)+512]) * SCALE + mask[b,j]
// Fixed-shift softmax (exp(s-8), exact), lane-partial row sums reduced once at end.
// K/RK/RQ staged via global_load_lds (pre-swizzled source, linear LDS), issued for
// jt+1 after barrier#2 so load latency hides under softmax+PV. 2 barriers per jt.
// LDS = 81,920 B -> 2 blocks/CU.
__global__ void __launch_bounds__(256, 2) attn_fused(
    const u16* __restrict__ qg, const u16* __restrict__ kg, const u16* __restrict__ vtg,
    const u16* __restrict__ rkg, const u16* __restrict__ rqg,
    const float* __restrict__ mask, float* __restrict__ out) {
  __shared__ __align__(16) u16 Ks[64][64];     //  8192
  __shared__ __align__(16) u16 Ps[64][64];     //  8192
  __shared__ __align__(16) u16 RKs[128][64];   // 16384
  __shared__ __align__(16) u16 RQs[128][64];   // 16384
  __shared__ __align__(16) u16 Ts[64][128];    // 16384
  __shared__ __align__(16) u16 Us[64][128];    // 16384

  // XCD swizzle: 8 XCDs, 128 consecutive blocks each
  const int bx = ((blockIdx.x & 7) << 7) | (blockIdx.x >> 3);
  const int it = bx & 15, bn = bx >> 4;
  const int b = bn >> 4, n = bn & 15;
  const int i0 = it * 64;
  const int tid = threadIdx.x, w = tid >> 6, lane = tid & 63;
  const int lj = lane & 15, lg = lane >> 4;

  const u16* qh = qg + (size_t)bn * 65536;
  const u16* kh = kg + (size_t)bn * 65536;
  const u16* vth = vtg + (size_t)bn * 65536;
  const u16* rkh = rkg + (size_t)n * 65600;
  const u16* rqh = rqg + (size_t)n * 65600;
  const float* mk = mask + (size_t)b * 1024;

  // ---- GLL16 staging setup: lane l writes LDS slot base+l*16B (linear);
  // slot (row, gslot) holds logical granule g = gslot ^ (row&7)  (SWZ-consistent).
  // row = (wave_chunk)*8 + (lane>>3); gslot = lane&7 -> g = (lane&7)^(lane>>3).
  const int l8 = lane >> 3, gK = (lane & 7) ^ l8;
  const u16* kb0  = kh  + (size_t)((w * 2 + 0) * 8 + l8) * 64 + gK * 8;
  const u16* kb1  = kh  + (size_t)((w * 2 + 1) * 8 + l8) * 64 + gK * 8;
  const u16* rkb0 = rkh + (size_t)((w * 4 + 0) * 8 + l8) * 64 + gK * 8;
  const u16* rkb1 = rkh + (size_t)((w * 4 + 1) * 8 + l8) * 64 + gK * 8;
  const u16* rkb2 = rkh + (size_t)((w * 4 + 2) * 8 + l8) * 64 + gK * 8;
  const u16* rkb3 = rkh + (size_t)((w * 4 + 3) * 8 + l8) * 64 + gK * 8;
  const u16* rqb0 = rqh + (size_t)((w * 4 + 0) * 8 + l8) * 64 + gK * 8;
  const u16* rqb1 = rqh + (size_t)((w * 4 + 1) * 8 + l8) * 64 + gK * 8;
  const u16* rqb2 = rqh + (size_t)((w * 4 + 2) * 8 + l8) * 64 + gK * 8;
  const u16* rqb3 = rqh + (size_t)((w * 4 + 3) * 8 + l8) * 64 + gK * 8;
  u16* ksd0 = &Ks[0][0]  + (w * 2 + 0) * 512;
  u16* ksd1 = &Ks[0][0]  + (w * 2 + 1) * 512;
  u16* rkd0 = &RKs[0][0] + (w * 4 + 0) * 512;
  u16* rkd1 = &RKs[0][0] + (w * 4 + 1) * 512;
  u16* rkd2 = &RKs[0][0] + (w * 4 + 2) * 512;
  u16* rkd3 = &RKs[0][0] + (w * 4 + 3) * 512;
  u16* rqd0 = &RQs[0][0] + (w * 4 + 0) * 512;
  u16* rqd1 = &RQs[0][0] + (w * 4 + 1) * 512;
  u16* rqd2 = &RQs[0][0] + (w * 4 + 2) * 512;
  u16* rqd3 = &RQs[0][0] + (w * 4 + 3) * 512;

#define STAGE_TILE(J0N) do { \
    const int ddn_ = i0 - (J0N) + 512; \
    int w0n_ = ddn_ - 63; w0n_ = w0n_ < 0 ? 0 : (w0n_ > 897 ? 897 : w0n_); \
    int w0qn_ = (1024 - ddn_) - 63; w0qn_ = w0qn_ < 0 ? 0 : (w0qn_ > 897 ? 897 : w0qn_); \
    GLL16(kb0 + (size_t)(J0N) * 64, ksd0); \
    GLL16(kb1 + (size_t)(J0N) * 64, ksd1); \
    GLL16(rkb0 + (size_t)w0n_ * 64, rkd0); \
    GLL16(rkb1 + (size_t)w0n_ * 64, rkd1); \
    GLL16(rkb2 + (size_t)w0n_ * 64, rkd2); \
    GLL16(rkb3 + (size_t)w0n_ * 64, rkd3); \
    GLL16(rqb0 + (size_t)w0qn_ * 64, rqd0); \
    GLL16(rqb1 + (size_t)w0qn_ * 64, rqd1); \
    GLL16(rqb2 + (size_t)w0qn_ * 64, rqd2); \
    GLL16(rqb3 + (size_t)w0qn_ * 64, rqd3); \
  } while (0)

  // Q fragment -> registers (wave-private rows, constant over jt)
  bf16x8 aq[2];
  #pragma unroll
  for (int k2 = 0; k2 < 2; ++k2)
    aq[k2] = *(const bf16x8*)(qh + (size_t)(i0 + w * 16 + lj) * 64 + k2 * 32 + lg * 8);

  // V row-base pointers (per-lane, advance by j0 per jt)
  const u16* vrow[4];
  #pragma unroll
  for (int d = 0; d < 4; ++d)
    vrow[d] = vth + (size_t)(d * 16 + lj) * 1024 + lg * 8;

  // softmax per-lane constants
  const int swj = (lj & 7) << 3;              // Us swizzle (j_loc&7 == lj&7)
  int baseT[4], swi[4], baseP[4];
  #pragma unroll
  for (int r = 0; r < 4; ++r) {
    const int il = w * 16 + lg * 4 + r;
    baseT[r] = il * 128;
    swi[r] = (il & 7) << 3;
    baseP[r] = il * 64;
  }
  const u16* Ts_f = &Ts[0][0];
  const u16* Us_f = &Us[0][0];
  u16* Ps_f = &Ps[0][0];

  float lsum[4] = {0.f, 0.f, 0.f, 0.f};
  f32x4 accO[4] = {};

  STAGE_TILE(0);  // prologue

  for (int jt = 0; jt < 16; ++jt) {
    const int j0 = jt * 64;
    const int dd = i0 - j0 + 512;
    int w0 = dd - 63; w0 = w0 < 0 ? 0 : (w0 > 897 ? 897 : w0);
    int w0q = (1024 - dd) - 63; w0q = w0q < 0 ? 0 : (w0q > 897 ? 897 : w0q);

    __syncthreads();  // staged K/RK/RQ visible (per-wave vmcnt drained at barrier)

    bf16x8 ak[2];
    #pragma unroll
    for (int k2 = 0; k2 < 2; ++k2) {
      const int kr = w * 16 + lj;
      ak[k2] = *(const bf16x8*)(&Ks[kr][SWZ(kr, k2 * 32 + lg * 8)]);
    }
    // c2c
    f32x4 scc[4];
    #pragma unroll
    for (int jf = 0; jf < 4; ++jf) {
      scc[jf] = (f32x4){0.f, 0.f, 0.f, 0.f};
      #pragma unroll
      for (int k2 = 0; k2 < 2; ++k2) {
        const int kr = jf * 16 + lj;
        bf16x8 bk8 = *(const bf16x8*)(&Ks[kr][SWZ(kr, k2 * 32 + lg * 8)]);
        scc[jf] = MFMA16(aq[k2], bk8, scc[jf]);
      }
    }
    // T[i,t] = q_i.relk[w0+t] (wave-private rows); U[j,t] = k_j.relq[w0q+t]
    #pragma unroll
    for (int tf = 0; tf < 8; ++tf) {
      f32x4 t_ = {0.f, 0.f, 0.f, 0.f};
      f32x4 u_ = {0.f, 0.f, 0.f, 0.f};
      #pragma unroll
      for (int k2 = 0; k2 < 2; ++k2) {
        const int rr = tf * 16 + lj;
        bf16x8 brk = *(const bf16x8*)(&RKs[rr][SWZ(rr, k2 * 32 + lg * 8)]);
        bf16x8 brq = *(const bf16x8*)(&RQs[rr][SWZ(rr, k2 * 32 + lg * 8)]);
        t_ = MFMA16(aq[k2], brk, t_);
        u_ = MFMA16(ak[k2], brq, u_);
      }
      #pragma unroll
      for (int r = 0; r < 4; ++r) {
        const int tr = w * 16 + lg * 4 + r;
        Ts[tr][SWZ(tr, tf * 16 + lj)] = f2bf(t_[r]);
        Us[tr][SWZ(tr, tf * 16 + lj)] = f2bf(u_[r]);
      }
    }
    __syncthreads();  // T/U visible; K/RK/RQ fully consumed

    if (jt < 15) STAGE_TILE(j0 + 64);  // next tile: latency hides under softmax+PV

    // V tile -> registers (latency hides under softmax)
    bf16x8 vreg[8];
    #pragma unroll
    for (int jk = 0; jk < 2; ++jk)
      #pragma unroll
      for (int d = 0; d < 4; ++d)
        vreg[jk * 4 + d] = *(const bf16x8*)(vrow[d] + j0 + jk * 32);

    // scores + fixed-shift softmax: p = exp(s - 8), lane-partial row sums
    const int E = dd + w * 16 + lg * 4 - lj;  // x1 = clip(E + r - jf*16, 0, 1024)
    const int C2 = 1024 - w0q;
    float mjs[4];
    #pragma unroll
    for (int jf = 0; jf < 4; ++jf)
      mjs[jf] = mk[j0 + jf * 16 + lj] - 8.f;
    #pragma unroll
    for (int jf = 0; jf < 4; ++jf) {
      #pragma unroll
      for (int r = 0; r < 4; ++r) {
        int x1 = E + r - jf * 16;
        x1 = x1 < 0 ? 0 : (x1 > 1024 ? 1024 : x1);
        const float tT = bf2f(Ts_f[baseT[r] + ((x1 - w0) ^ swi[r])]);
        const float tU = bf2f(Us_f[(jf * 16 + lj) * 128 + ((C2 - x1) ^ swj)]);
        const float s = fmaf(scc[jf][r] + tT + tU, SCALE, mjs[jf]);
        const float p = __expf(s);
        lsum[r] += p;
        Ps_f[baseP[r] + ((jf * 16 + lj) ^ (swi[r] & 56))] = f2bf(p);
      }
    }
    // PV: O[i,d] += P[i,j] * V[j,d]  (P rows wave-private; V in registers)
    #pragma unroll
    for (int jk = 0; jk < 2; ++jk) {
      const int pr = w * 16 + lj;
      bf16x8 ap = *(const bf16x8*)(&Ps[pr][SWZ(pr, jk * 32 + lg * 8)]);
      #pragma unroll
      for (int d = 0; d < 4; ++d)
        accO[d] = MFMA16(ap, vreg[jk * 4 + d], accO[d]);
    }
  }

  // final row-sum reduce (j is distributed over the 16 lj lanes)
  #pragma unroll
  for (int off = 1; off < 16; off <<= 1)
    #pragma unroll
    for (int r = 0; r < 4; ++r)
      lsum[r] += __shfl_xor(lsum[r], off);

  #pragma unroll
  for (int r = 0; r < 4; ++r) {
    const float inv = 1.f / lsum[r];
    const int i = i0 + w * 16 + lg * 4 + r;
    #pragma unroll
    for (int d = 0; d < 4; ++d)
      out[((size_t)b * 1024 + i) * 1024 + n * 64 + d * 16 + lj] = accO[d][r] * inv;
  }
#undef STAGE_TILE
}

extern "C" void kernel_launch(void* const* d_in, const int* in_sizes, int n_in,
                              void* d_out, int out_size, void* d_ws, size_t ws_size,
                              hipStream_t stream) {
  const float* hs   = (const float*)d_in[0];
  const float* mask = (const float*)d_in[1];
  const float* rel  = (const float*)d_in[2];
  const float* Wq   = (const float*)d_in[3];
  const float* bq   = (const float*)d_in[4];
  const float* Wk   = (const float*)d_in[5];
  const float* bk   = (const float*)d_in[6];
  const float* Wv   = (const float*)d_in[7];
  const float* bv   = (const float*)d_in[8];
  const float* Wpk  = (const float*)d_in[9];
  const float* bpk  = (const float*)d_in[10];
  const float* Wpq  = (const float*)d_in[11];
  const float* bpq  = (const float*)d_in[12];
  float* outp = (float*)d_out;

  u16* p = (u16*)d_ws;
  u16* hsb  = p; p += (size_t)4096 * 1024;
  u16* relb = p; p += (size_t)1025 * 1024;
  u16* WqT  = p; p += (size_t)1024 * 1024;   // WqT/WkT/WvT consecutive
  u16* WkT  = p; p += (size_t)1024 * 1024;
  u16* WvT  = p; p += (size_t)1024 * 1024;
  u16* WpkT = p; p += (size_t)1024 * 1024;   // WpkT/WpqT consecutive
  u16* WpqT = p; p += (size_t)1024 * 1024;
  u16* qws  = p; p += (size_t)4096 * 1024;   // q/k/v consecutive
  u16* kws  = p; p += (size_t)4096 * 1024;
  u16* vws  = p; p += (size_t)4096 * 1024;
  u16* rkws = p; p += (size_t)16 * 1025 * 64;  // rk/rq consecutive
  u16* rqws = p; p += (size_t)16 * 1025 * 64;
  if ((size_t)((char*)p - (char*)d_ws) > ws_size) return;  // ws too small: bail
  (void)kws; (void)rqws;

  cvt_bf16<<<4096, 256, 0, stream>>>(hs, hsb, 1048576);
  cvt_bf16<<<1025, 256, 0, stream>>>(rel, relb, 262400);
  transp5_bf16<<<dim3(32, 32, 5), 256, 0, stream>>>(Wq, Wk, Wv, Wpk, Wpq,
                                                    WqT, WkT, WvT, WpkT, WpqT);

  gemm_multi<<<dim3(32, 24), 256, 0, stream>>>(hsb, WqT, bq, bk, bv, qws, 4096, 0);
  gemm_multi<<<dim3(9, 16),  256, 0, stream>>>(relb, WpkT, bpk, bpq, bpq, rkws, 1025, 1);

  attn_fused<<<1024, 256, 0, stream>>>(qws, kws, vws, rkws, rqws, mask, outp);
}

// Round 7
// 213.765 us; speedup vs baseline: 2.2611x; 1.0725x over previous
//
#include <hip/hip_runtime.h>
#include <stdint.h>

typedef unsigned short u16;
typedef __bf16 bf16_t;
typedef bf16_t bf16x8 __attribute__((ext_vector_type(8)));
typedef float f32x4 __attribute__((ext_vector_type(4)));

__device__ __forceinline__ u16 f2bf(float f) {
  union { float f; unsigned int u; } v; v.f = f;
  return (u16)((v.u + 0x7FFFu + ((v.u >> 16) & 1u)) >> 16);
}
__device__ __forceinline__ float bf2f(u16 b) {
  union { unsigned int u; float f; } v; v.u = ((unsigned int)b) << 16;
  return v.f;
}
__device__ __forceinline__ unsigned pk2bf(float a, float b) {
  return (unsigned)f2bf(a) | ((unsigned)f2bf(b) << 16);
}

#define MFMA16(a, b, c) __builtin_amdgcn_mfma_f32_16x16x32_bf16((a), (b), (c), 0, 0, 0)
#define GLL16(g, l) __builtin_amdgcn_global_load_lds( \
    (const __attribute__((address_space(1))) void*)(g), \
    (__attribute__((address_space(3))) void*)(l), 16, 0, 0)

// granule-XOR swizzle: permutes 8-u16 granules within a row; same formula on
// write and read -> bijective & self-consistent.
#define SWZ(row, col) ((col) ^ (((row) & 7) << 3))

#define SCALE 0.07216878364870323f  // 1/sqrt(3*64)

// ---------------- fp32 -> bf16 elementwise ----------------
__global__ void cvt_bf16(const float* __restrict__ in, u16* __restrict__ out, int n4) {
  int i = blockIdx.x * 256 + threadIdx.x;
  if (i >= n4) return;
  float4 v = ((const float4*)in)[i];
  ushort4 o;
  o.x = f2bf(v.x); o.y = f2bf(v.y); o.z = f2bf(v.z); o.w = f2bf(v.w);
  ((ushort4*)out)[i] = o;
}

// ---------------- 5x fused 1024x1024 fp32 -> bf16 transpose ----------------
__global__ void transp5_bf16(const float* __restrict__ i0, const float* __restrict__ i1,
                             const float* __restrict__ i2, const float* __restrict__ i3,
                             const float* __restrict__ i4,
                             u16* __restrict__ o0, u16* __restrict__ o1,
                             u16* __restrict__ o2, u16* __restrict__ o3,
                             u16* __restrict__ o4) {
  __shared__ float t[32][33];
  const float* in;
  u16* out;
  switch (blockIdx.z) {
    case 0: in = i0; out = o0; break;
    case 1: in = i1; out = o1; break;
    case 2: in = i2; out = o2; break;
    case 3: in = i3; out = o3; break;
    default: in = i4; out = o4; break;
  }
  int tx = threadIdx.x & 31, ty = threadIdx.x >> 5;
  int x0 = blockIdx.x * 32, y0 = blockIdx.y * 32;
  #pragma unroll
  for (int i = ty; i < 32; i += 8)
    t[i][tx] = in[(size_t)(y0 + i) * 1024 + x0 + tx];
  __syncthreads();
  #pragma unroll
  for (int i = ty; i < 32; i += 8)
    out[(size_t)(x0 + i) * 1024 + y0 + tx] = f2bf(t[tx][i]);
}

// ---------------- fused multi-matrix bf16 GEMM ----------------
// C[M,1024] = A[M,1024] * BT_mat[1024,1024]^T + bias_mat, mat = blockIdx.y>>3
// rel==0 (qkv, grid 32x24): mat 0,1 -> out[(b*16+h)][s][d]; mat 2 -> out[(b*16+h)][d][s]
// rel==1 (grid 9x16):       mat 0,1 -> out + mat*1049600, layout [h][r][d]
__global__ void __launch_bounds__(256) gemm_multi(
    const u16* __restrict__ A, const u16* __restrict__ BT,
    const float* __restrict__ b0, const float* __restrict__ b1, const float* __restrict__ b2,
    u16* __restrict__ out, int M, int rel) {
  __shared__ __align__(16) u16 As[4096];
  __shared__ __align__(16) u16 Bs[4096];
  const int K = 1024;
  const int mat = blockIdx.y >> 3;
  const u16* BTm = BT + (size_t)mat * 1048576;
  const float* bias = (mat == 0) ? b0 : ((mat == 1) ? b1 : b2);
  const int m0 = blockIdx.x * 128, n0 = (blockIdx.y & 7) * 128;
  const int w = threadIdx.x >> 6, lane = threadIdx.x & 63;
  const int lj = lane & 15, lg = lane >> 4;
  const int wm = (w >> 1) * 64, wn = (w & 1) * 64;

  f32x4 acc[4][4] = {};

  const int chunk0 = w * 128 + lane;
  const int chunk1 = chunk0 + 64;
  int r0 = chunk0 >> 2, s0 = (chunk0 & 3) * 8;
  int r1 = chunk1 >> 2, s1 = (chunk1 & 3) * 8;
  int ar0 = m0 + r0; if (ar0 >= M) ar0 = M - 1;
  int ar1 = m0 + r1; if (ar1 >= M) ar1 = M - 1;
  const u16* ga0 = A + (size_t)ar0 * K + s0;
  const u16* ga1 = A + (size_t)ar1 * K + s1;
  const u16* gb0 = BTm + (size_t)(n0 + r0) * K + s0;
  const u16* gb1 = BTm + (size_t)(n0 + r1) * K + s1;
  u16* lA0 = As + (w * 2 + 0) * 512;
  u16* lA1 = As + (w * 2 + 1) * 512;
  u16* lB0 = Bs + (w * 2 + 0) * 512;
  u16* lB1 = Bs + (w * 2 + 1) * 512;

  for (int k0 = 0; k0 < K; k0 += 32) {
    GLL16(ga0 + k0, lA0);
    GLL16(ga1 + k0, lA1);
    GLL16(gb0 + k0, lB0);
    GLL16(gb1 + k0, lB1);
    __syncthreads();
    bf16x8 af[4], bf8[4];
    #pragma unroll
    for (int mf = 0; mf < 4; ++mf)
      af[mf] = *(const bf16x8*)(As + (wm + mf * 16 + lj) * 32 + lg * 8);
    #pragma unroll
    for (int nf = 0; nf < 4; ++nf)
      bf8[nf] = *(const bf16x8*)(Bs + (wn + nf * 16 + lj) * 32 + lg * 8);
    #pragma unroll
    for (int mf = 0; mf < 4; ++mf)
      #pragma unroll
      for (int nf = 0; nf < 4; ++nf)
        acc[mf][nf] = MFMA16(af[mf], bf8[nf], acc[mf][nf]);
    __syncthreads();
  }

  #pragma unroll
  for (int mf = 0; mf < 4; ++mf) {
    #pragma unroll
    for (int nf = 0; nf < 4; ++nf) {
      const int j = n0 + wn + nf * 16 + lj;
      const float bj = bias[j];
      #pragma unroll
      for (int r = 0; r < 4; ++r) {
        const int i = m0 + wm + mf * 16 + lg * 4 + r;
        if (i >= M) continue;
        const u16 val = f2bf(acc[mf][nf][r] + bj);
        if (rel) {
          out[(size_t)mat * 1049600 + (size_t)(j >> 6) * 65600 + (size_t)i * 64 + (j & 63)] = val;
        } else if (mat < 2) {
          out[(size_t)mat * 4194304 +
              (size_t)(((i >> 10) << 4) + (j >> 6)) * 65536 + (size_t)(i & 1023) * 64 + (j & 63)] = val;
        } else {
          out[(size_t)2 * 4194304 +
              (size_t)(((i >> 10) << 4) + (j >> 6)) * 65536 + (size_t)(j & 63) * 1024 + (i & 1023)] = val;
        }
      }
    }
  }
}

// ---------------- fused disentangled attention ----------------
// grid: 1024 blocks = (b*16+n)*16 + i_tile ; block: 256 threads (4 waves)
// scores[i,j] = (q_i.k_j + q_i.relk[clip(i-j)+512] + k_j.relq[clip(j-i)+512]) * SCALE + mask[b,j]
// Fixed-shift softmax (exp(s-8), exact). T/U produced TRANSPOSED:
// T^T = mfma(RK,Q), U^T = mfma(RQ,K) -> lane holds 4 consecutive cols of one row
// -> packed ds_write_b64 (bit-pack, no inline asm). 2 barriers/jt; K/RK/RQ staged
// via global_load_lds for jt+1 after barrier#2. LDS = 81,920 B -> 2 blocks/CU.
__global__ void __launch_bounds__(256, 2) attn_fused(
    const u16* __restrict__ qg, const u16* __restrict__ kg, const u16* __restrict__ vtg,
    const u16* __restrict__ rkg, const u16* __restrict__ rqg,
    const float* __restrict__ mask, float* __restrict__ out) {
  __shared__ __align__(16) u16 Ks[64][64];     //  8192
  __shared__ __align__(16) u16 Ps[64][64];     //  8192
  __shared__ __align__(16) u16 RKs[128][64];   // 16384
  __shared__ __align__(16) u16 RQs[128][64];   // 16384
  __shared__ __align__(16) u16 Ts[64][128];    // 16384
  __shared__ __align__(16) u16 Us[64][128];    // 16384

  // XCD swizzle: 8 XCDs, 128 consecutive blocks each
  const int bx = ((blockIdx.x & 7) << 7) | (blockIdx.x >> 3);
  const int it = bx & 15, bn = bx >> 4;
  const int b = bn >> 4, n = bn & 15;
  const int i0 = it * 64;
  const int tid = threadIdx.x, w = tid >> 6, lane = tid & 63;
  const int lj = lane & 15, lg = lane >> 4;

  const u16* qh = qg + (size_t)bn * 65536;
  const u16* kh = kg + (size_t)bn * 65536;
  const u16* vth = vtg + (size_t)bn * 65536;
  const u16* rkh = rkg + (size_t)n * 65600;
  const u16* rqh = rqg + (size_t)n * 65600;
  const float* mk = mask + (size_t)b * 1024;

  // ---- GLL16 staging setup: lane l writes LDS slot base+l*16B (linear);
  // slot (row, gslot) holds logical granule g = gslot ^ (row&7)  (SWZ-consistent).
  const int l8 = lane >> 3, gK = (lane & 7) ^ l8;
  const u16* kb0  = kh  + (size_t)((w * 2 + 0) * 8 + l8) * 64 + gK * 8;
  const u16* kb1  = kh  + (size_t)((w * 2 + 1) * 8 + l8) * 64 + gK * 8;
  const u16* rkb0 = rkh + (size_t)((w * 4 + 0) * 8 + l8) * 64 + gK * 8;
  const u16* rkb1 = rkh + (size_t)((w * 4 + 1) * 8 + l8) * 64 + gK * 8;
  const u16* rkb2 = rkh + (size_t)((w * 4 + 2) * 8 + l8) * 64 + gK * 8;
  const u16* rkb3 = rkh + (size_t)((w * 4 + 3) * 8 + l8) * 64 + gK * 8;
  const u16* rqb0 = rqh + (size_t)((w * 4 + 0) * 8 + l8) * 64 + gK * 8;
  const u16* rqb1 = rqh + (size_t)((w * 4 + 1) * 8 + l8) * 64 + gK * 8;
  const u16* rqb2 = rqh + (size_t)((w * 4 + 2) * 8 + l8) * 64 + gK * 8;
  const u16* rqb3 = rqh + (size_t)((w * 4 + 3) * 8 + l8) * 64 + gK * 8;
  u16* ksd0 = &Ks[0][0]  + (w * 2 + 0) * 512;
  u16* ksd1 = &Ks[0][0]  + (w * 2 + 1) * 512;
  u16* rkd0 = &RKs[0][0] + (w * 4 + 0) * 512;
  u16* rkd1 = &RKs[0][0] + (w * 4 + 1) * 512;
  u16* rkd2 = &RKs[0][0] + (w * 4 + 2) * 512;
  u16* rkd3 = &RKs[0][0] + (w * 4 + 3) * 512;
  u16* rqd0 = &RQs[0][0] + (w * 4 + 0) * 512;
  u16* rqd1 = &RQs[0][0] + (w * 4 + 1) * 512;
  u16* rqd2 = &RQs[0][0] + (w * 4 + 2) * 512;
  u16* rqd3 = &RQs[0][0] + (w * 4 + 3) * 512;

#define STAGE_TILE(J0N) do { \
    const int ddn_ = i0 - (J0N) + 512; \
    int w0n_ = ddn_ - 63; w0n_ = w0n_ < 0 ? 0 : (w0n_ > 897 ? 897 : w0n_); \
    int w0qn_ = (1024 - ddn_) - 63; w0qn_ = w0qn_ < 0 ? 0 : (w0qn_ > 897 ? 897 : w0qn_); \
    GLL16(kb0 + (size_t)(J0N) * 64, ksd0); \
    GLL16(kb1 + (size_t)(J0N) * 64, ksd1); \
    GLL16(rkb0 + (size_t)w0n_ * 64, rkd0); \
    GLL16(rkb1 + (size_t)w0n_ * 64, rkd1); \
    GLL16(rkb2 + (size_t)w0n_ * 64, rkd2); \
    GLL16(rkb3 + (size_t)w0n_ * 64, rkd3); \
    GLL16(rqb0 + (size_t)w0qn_ * 64, rqd0); \
    GLL16(rqb1 + (size_t)w0qn_ * 64, rqd1); \
    GLL16(rqb2 + (size_t)w0qn_ * 64, rqd2); \
    GLL16(rqb3 + (size_t)w0qn_ * 64, rqd3); \
  } while (0)

  // Q fragment -> registers (wave-private rows, constant over jt)
  bf16x8 aq[2];
  #pragma unroll
  for (int k2 = 0; k2 < 2; ++k2)
    aq[k2] = *(const bf16x8*)(qh + (size_t)(i0 + w * 16 + lj) * 64 + k2 * 32 + lg * 8);

  // V row-base pointers (per-lane, advance by j0 per jt)
  const u16* vrow[4];
  #pragma unroll
  for (int d = 0; d < 4; ++d)
    vrow[d] = vth + (size_t)(d * 16 + lj) * 1024 + lg * 8;

  // per-lane constants
  const int swlj = (lj & 7) << 3;             // swizzle for rows ≡ lj (mod 16)
  u16* tsrow = &Ts[w * 16 + lj][0];           // transposed-production write rows
  u16* usrow = &Us[w * 16 + lj][0];
  int baseT[4], swi[4], baseP[4];
  #pragma unroll
  for (int r = 0; r < 4; ++r) {
    const int il = w * 16 + lg * 4 + r;
    baseT[r] = il * 128;
    swi[r] = (il & 7) << 3;
    baseP[r] = il * 64;
  }
  const u16* Ts_f = &Ts[0][0];
  const u16* Us_f = &Us[0][0];
  u16* Ps_f = &Ps[0][0];

  float lsum[4] = {0.f, 0.f, 0.f, 0.f};
  f32x4 accO[4] = {};

  STAGE_TILE(0);  // prologue

  for (int jt = 0; jt < 16; ++jt) {
    const int j0 = jt * 64;
    const int dd = i0 - j0 + 512;
    int w0 = dd - 63; w0 = w0 < 0 ? 0 : (w0 > 897 ? 897 : w0);
    int w0q = (1024 - dd) - 63; w0q = w0q < 0 ? 0 : (w0q > 897 ? 897 : w0q);

    __syncthreads();  // staged K/RK/RQ visible

    bf16x8 ak[2];
    #pragma unroll
    for (int k2 = 0; k2 < 2; ++k2) {
      const int kr = w * 16 + lj;
      ak[k2] = *(const bf16x8*)(&Ks[kr][SWZ(kr, k2 * 32 + lg * 8)]);
    }
    __builtin_amdgcn_s_setprio(1);
    // c2c
    f32x4 scc[4];
    #pragma unroll
    for (int jf = 0; jf < 4; ++jf) {
      scc[jf] = (f32x4){0.f, 0.f, 0.f, 0.f};
      #pragma unroll
      for (int k2 = 0; k2 < 2; ++k2) {
        const int kr = jf * 16 + lj;
        bf16x8 bk8 = *(const bf16x8*)(&Ks[kr][SWZ(kr, k2 * 32 + lg * 8)]);
        scc[jf] = MFMA16(aq[k2], bk8, scc[jf]);
      }
    }
    // Transposed production: T^T = mfma(RK, Q), U^T = mfma(RQ, K).
    // Lane holds 4 consecutive t-cols of row (w*16+lj) -> packed b64 write.
    #pragma unroll
    for (int tf = 0; tf < 8; ++tf) {
      f32x4 t_ = {0.f, 0.f, 0.f, 0.f};
      f32x4 u_ = {0.f, 0.f, 0.f, 0.f};
      #pragma unroll
      for (int k2 = 0; k2 < 2; ++k2) {
        const int rr = tf * 16 + lj;
        bf16x8 brk = *(const bf16x8*)(&RKs[rr][SWZ(rr, k2 * 32 + lg * 8)]);
        bf16x8 brq = *(const bf16x8*)(&RQs[rr][SWZ(rr, k2 * 32 + lg * 8)]);
        t_ = MFMA16(brk, aq[k2], t_);
        u_ = MFMA16(brq, ak[k2], u_);
      }
      uint2 tp, up;
      tp.x = pk2bf(t_[0], t_[1]); tp.y = pk2bf(t_[2], t_[3]);
      up.x = pk2bf(u_[0], u_[1]); up.y = pk2bf(u_[2], u_[3]);
      const int cb = (tf * 16 + lg * 4) ^ swlj;
      *(uint2*)(tsrow + cb) = tp;
      *(uint2*)(usrow + cb) = up;
    }
    __builtin_amdgcn_s_setprio(0);
    __syncthreads();  // T/U visible; K/RK/RQ fully consumed

    if (jt < 15) STAGE_TILE(j0 + 64);  // next tile: latency hides under softmax+PV

    // V tile -> registers (latency hides under softmax)
    bf16x8 vreg[8];
    #pragma unroll
    for (int jk = 0; jk < 2; ++jk)
      #pragma unroll
      for (int d = 0; d < 4; ++d)
        vreg[jk * 4 + d] = *(const bf16x8*)(vrow[d] + j0 + jk * 32);

    // scores + fixed-shift softmax: p = exp(s - 8), lane-partial row sums
    const int E = dd + w * 16 + lg * 4 - lj;  // x1 = clip(E + r - jf*16, 0, 1024)
    const int C2 = 1024 - w0q;
    float mjs[4];
    #pragma unroll
    for (int jf = 0; jf < 4; ++jf)
      mjs[jf] = mk[j0 + jf * 16 + lj] - 8.f;
    #pragma unroll
    for (int jf = 0; jf < 4; ++jf) {
      #pragma unroll
      for (int r = 0; r < 4; ++r) {
        int x1 = E + r - jf * 16;
        x1 = x1 < 0 ? 0 : (x1 > 1024 ? 1024 : x1);
        const float tT = bf2f(Ts_f[baseT[r] + ((x1 - w0) ^ swi[r])]);
        const float tU = bf2f(Us_f[(jf * 16 + lj) * 128 + ((C2 - x1) ^ swlj)]);
        const float s = fmaf(scc[jf][r] + tT + tU, SCALE, mjs[jf]);
        const float p = __expf(s);
        lsum[r] += p;
        Ps_f[baseP[r] + ((jf * 16 + lj) ^ (swi[r] & 56))] = f2bf(p);
      }
    }
    // PV: O[i,d] += P[i,j] * V[j,d]  (P rows wave-private; V in registers)
    __builtin_amdgcn_s_setprio(1);
    #pragma unroll
    for (int jk = 0; jk < 2; ++jk) {
      const int pr = w * 16 + lj;
      bf16x8 ap = *(const bf16x8*)(&Ps[pr][SWZ(pr, jk * 32 + lg * 8)]);
      #pragma unroll
      for (int d = 0; d < 4; ++d)
        accO[d] = MFMA16(ap, vreg[jk * 4 + d], accO[d]);
    }
    __builtin_amdgcn_s_setprio(0);
  }

  // final row-sum reduce (j is distributed over the 16 lj lanes)
  #pragma unroll
  for (int off = 1; off < 16; off <<= 1)
    #pragma unroll
    for (int r = 0; r < 4; ++r)
      lsum[r] += __shfl_xor(lsum[r], off);

  #pragma unroll
  for (int r = 0; r < 4; ++r) {
    const float inv = 1.f / lsum[r];
    const int i = i0 + w * 16 + lg * 4 + r;
    #pragma unroll
    for (int d = 0; d < 4; ++d)
      out[((size_t)b * 1024 + i) * 1024 + n * 64 + d * 16 + lj] = accO[d][r] * inv;
  }
#undef STAGE_TILE
}

extern "C" void kernel_launch(void* const* d_in, const int* in_sizes, int n_in,
                              void* d_out, int out_size, void* d_ws, size_t ws_size,
                              hipStream_t stream) {
  const float* hs   = (const float*)d_in[0];
  const float* mask = (const float*)d_in[1];
  const float* rel  = (const float*)d_in[2];
  const float* Wq   = (const float*)d_in[3];
  const float* bq   = (const float*)d_in[4];
  const float* Wk   = (const float*)d_in[5];
  const float* bk   = (const float*)d_in[6];
  const float* Wv   = (const float*)d_in[7];
  const float* bv   = (const float*)d_in[8];
  const float* Wpk  = (const float*)d_in[9];
  const float* bpk  = (const float*)d_in[10];
  const float* Wpq  = (const float*)d_in[11];
  const float* bpq  = (const float*)d_in[12];
  float* outp = (float*)d_out;

  u16* p = (u16*)d_ws;
  u16* hsb  = p; p += (size_t)4096 * 1024;
  u16* relb = p; p += (size_t)1025 * 1024;
  u16* WqT  = p; p += (size_t)1024 * 1024;   // WqT/WkT/WvT consecutive
  u16* WkT  = p; p += (size_t)1024 * 1024;
  u16* WvT  = p; p += (size_t)1024 * 1024;
  u16* WpkT = p; p += (size_t)1024 * 1024;   // WpkT/WpqT consecutive
  u16* WpqT = p; p += (size_t)1024 * 1024;
  u16* qws  = p; p += (size_t)4096 * 1024;   // q/k/v consecutive
  u16* kws  = p; p += (size_t)4096 * 1024;
  u16* vws  = p; p += (size_t)4096 * 1024;
  u16* rkws = p; p += (size_t)16 * 1025 * 64;  // rk/rq consecutive
  u16* rqws = p; p += (size_t)16 * 1025 * 64;
  if ((size_t)((char*)p - (char*)d_ws) > ws_size) return;  // ws too small: bail
  (void)kws; (void)rqws;

  cvt_bf16<<<4096, 256, 0, stream>>>(hs, hsb, 1048576);
  cvt_bf16<<<1025, 256, 0, stream>>>(rel, relb, 262400);
  transp5_bf16<<<dim3(32, 32, 5), 256, 0, stream>>>(Wq, Wk, Wv, Wpk, Wpq,
                                                    WqT, WkT, WvT, WpkT, WpqT);

  gemm_multi<<<dim3(32, 24), 256, 0, stream>>>(hsb, WqT, bq, bk, bv, qws, 4096, 0);
  gemm_multi<<<dim3(9, 16),  256, 0, stream>>>(relb, WpkT, bpk, bpq, bpq, rkws, 1025, 1);

  attn_fused<<<1024, 256, 0, stream>>>(qws, kws, vws, rkws, rqws, mask, outp);
}

// Round 9
// 212.943 us; speedup vs baseline: 2.2698x; 1.0039x over previous
//
#include <hip/hip_runtime.h>
#include <stdint.h>

typedef unsigned short u16;
typedef __bf16 bf16_t;
typedef bf16_t bf16x8 __attribute__((ext_vector_type(8)));
typedef float f32x4 __attribute__((ext_vector_type(4)));

__device__ __forceinline__ u16 f2bf(float f) {
  union { float f; unsigned int u; } v; v.f = f;
  return (u16)((v.u + 0x7FFFu + ((v.u >> 16) & 1u)) >> 16);
}
__device__ __forceinline__ float bf2f(u16 b) {
  union { unsigned int u; float f; } v; v.u = ((unsigned int)b) << 16;
  return v.f;
}
__device__ __forceinline__ unsigned pk2bf(float a, float b) {
  return (unsigned)f2bf(a) | ((unsigned)f2bf(b) << 16);
}

#define MFMA16(a, b, c) __builtin_amdgcn_mfma_f32_16x16x32_bf16((a), (b), (c), 0, 0, 0)
#define GLL16(g, l) __builtin_amdgcn_global_load_lds( \
    (const __attribute__((address_space(1))) void*)(g), \
    (__attribute__((address_space(3))) void*)(l), 16, 0, 0)

// granule-XOR swizzle: permutes 8-u16 granules within a row; same formula on
// write and read -> bijective & self-consistent.
#define SWZ(row, col) ((col) ^ (((row) & 7) << 3))

#define SCALE 0.07216878364870323f      // 1/sqrt(3*64)
#define SCALE_L2E 0.10411754546752362f  // SCALE * log2(e)
#define LOG2E 1.4426950408889634f
#define M8L2E -11.541560327111707f      // -8 * log2(e)

// ---------------- fp32 -> bf16 elementwise ----------------
__global__ void cvt_bf16(const float* __restrict__ in, u16* __restrict__ out, int n4) {
  int i = blockIdx.x * 256 + threadIdx.x;
  if (i >= n4) return;
  float4 v = ((const float4*)in)[i];
  ushort4 o;
  o.x = f2bf(v.x); o.y = f2bf(v.y); o.z = f2bf(v.z); o.w = f2bf(v.w);
  ((ushort4*)out)[i] = o;
}

// ---------------- 5x fused 1024x1024 fp32 -> bf16 transpose ----------------
__global__ void transp5_bf16(const float* __restrict__ i0, const float* __restrict__ i1,
                             const float* __restrict__ i2, const float* __restrict__ i3,
                             const float* __restrict__ i4,
                             u16* __restrict__ o0, u16* __restrict__ o1,
                             u16* __restrict__ o2, u16* __restrict__ o3,
                             u16* __restrict__ o4) {
  __shared__ float t[32][33];
  const float* in;
  u16* out;
  switch (blockIdx.z) {
    case 0: in = i0; out = o0; break;
    case 1: in = i1; out = o1; break;
    case 2: in = i2; out = o2; break;
    case 3: in = i3; out = o3; break;
    default: in = i4; out = o4; break;
  }
  int tx = threadIdx.x & 31, ty = threadIdx.x >> 5;
  int x0 = blockIdx.x * 32, y0 = blockIdx.y * 32;
  #pragma unroll
  for (int i = ty; i < 32; i += 8)
    t[i][tx] = in[(size_t)(y0 + i) * 1024 + x0 + tx];
  __syncthreads();
  #pragma unroll
  for (int i = ty; i < 32; i += 8)
    out[(size_t)(x0 + i) * 1024 + y0 + tx] = f2bf(t[tx][i]);
}

// ---------------- fused multi-matrix bf16 GEMM ----------------
// C[M,1024] = A[M,1024] * BT_mat[1024,1024]^T + bias_mat, mat = blockIdx.y>>3
// rel==0 (qkv, grid 32x24): mat 0,1 -> out[(b*16+h)][s][d]; mat 2 -> out[(b*16+h)][d][s]
// rel==1 (grid 9x16):       mat 0,1 -> out + mat*1049600, layout [h][r][d]
__global__ void __launch_bounds__(256) gemm_multi(
    const u16* __restrict__ A, const u16* __restrict__ BT,
    const float* __restrict__ b0, const float* __restrict__ b1, const float* __restrict__ b2,
    u16* __restrict__ out, int M, int rel) {
  __shared__ __align__(16) u16 As[4096];
  __shared__ __align__(16) u16 Bs[4096];
  const int K = 1024;
  const int mat = blockIdx.y >> 3;
  const u16* BTm = BT + (size_t)mat * 1048576;
  const float* bias = (mat == 0) ? b0 : ((mat == 1) ? b1 : b2);
  const int m0 = blockIdx.x * 128, n0 = (blockIdx.y & 7) * 128;
  const int w = threadIdx.x >> 6, lane = threadIdx.x & 63;
  const int lj = lane & 15, lg = lane >> 4;
  const int wm = (w >> 1) * 64, wn = (w & 1) * 64;

  f32x4 acc[4][4] = {};

  const int chunk0 = w * 128 + lane;
  const int chunk1 = chunk0 + 64;
  int r0 = chunk0 >> 2, s0 = (chunk0 & 3) * 8;
  int r1 = chunk1 >> 2, s1 = (chunk1 & 3) * 8;
  int ar0 = m0 + r0; if (ar0 >= M) ar0 = M - 1;
  int ar1 = m0 + r1; if (ar1 >= M) ar1 = M - 1;
  const u16* ga0 = A + (size_t)ar0 * K + s0;
  const u16* ga1 = A + (size_t)ar1 * K + s1;
  const u16* gb0 = BTm + (size_t)(n0 + r0) * K + s0;
  const u16* gb1 = BTm + (size_t)(n0 + r1) * K + s1;
  u16* lA0 = As + (w * 2 + 0) * 512;
  u16* lA1 = As + (w * 2 + 1) * 512;
  u16* lB0 = Bs + (w * 2 + 0) * 512;
  u16* lB1 = Bs + (w * 2 + 1) * 512;

  for (int k0 = 0; k0 < K; k0 += 32) {
    GLL16(ga0 + k0, lA0);
    GLL16(ga1 + k0, lA1);
    GLL16(gb0 + k0, lB0);
    GLL16(gb1 + k0, lB1);
    __syncthreads();
    bf16x8 af[4], bf8[4];
    #pragma unroll
    for (int mf = 0; mf < 4; ++mf)
      af[mf] = *(const bf16x8*)(As + (wm + mf * 16 + lj) * 32 + lg * 8);
    #pragma unroll
    for (int nf = 0; nf < 4; ++nf)
      bf8[nf] = *(const bf16x8*)(Bs + (wn + nf * 16 + lj) * 32 + lg * 8);
    #pragma unroll
    for (int mf = 0; mf < 4; ++mf)
      #pragma unroll
      for (int nf = 0; nf < 4; ++nf)
        acc[mf][nf] = MFMA16(af[mf], bf8[nf], acc[mf][nf]);
    __syncthreads();
  }

  #pragma unroll
  for (int mf = 0; mf < 4; ++mf) {
    #pragma unroll
    for (int nf = 0; nf < 4; ++nf) {
      const int j = n0 + wn + nf * 16 + lj;
      const float bj = bias[j];
      #pragma unroll
      for (int r = 0; r < 4; ++r) {
        const int i = m0 + wm + mf * 16 + lg * 4 + r;
        if (i >= M) continue;
        const u16 val = f2bf(acc[mf][nf][r] + bj);
        if (rel) {
          out[(size_t)mat * 1049600 + (size_t)(j >> 6) * 65600 + (size_t)i * 64 + (j & 63)] = val;
        } else if (mat < 2) {
          out[(size_t)mat * 4194304 +
              (size_t)(((i >> 10) << 4) + (j >> 6)) * 65536 + (size_t)(i & 1023) * 64 + (j & 63)] = val;
        } else {
          out[(size_t)2 * 4194304 +
              (size_t)(((i >> 10) << 4) + (j >> 6)) * 65536 + (size_t)(j & 63) * 1024 + (i & 1023)] = val;
        }
      }
    }
  }
}

// ---------------- fused disentangled attention ----------------
// grid: 1024 blocks = (b*16+n)*16 + i_tile ; block: 256 threads (4 waves)
// scores[i,j] = (q_i.k_j + q_i.relk[clip(i-j)+512] + k_j.relq[clip(j-i)+512]) * SCALE + mask[b,j]
// Fixed-shift softmax via exp2 fold (exact). T/U produced TRANSPOSED, bit-packed
// (pk2bf; cvt_pk asm REFUTED on HW, R8). Block-uniform no-clip fast path for
// interior tiles (dd in [63,961] -> x1 never clips). 2 barriers/jt; K/RK/RQ
// staged via global_load_lds for jt+1. LDS = 81,920 B -> 2 blocks/CU.
__global__ void __launch_bounds__(256, 2) attn_fused(
    const u16* __restrict__ qg, const u16* __restrict__ kg, const u16* __restrict__ vtg,
    const u16* __restrict__ rkg, const u16* __restrict__ rqg,
    const float* __restrict__ mask, float* __restrict__ out) {
  __shared__ __align__(16) u16 Ks[64][64];     //  8192
  __shared__ __align__(16) u16 Ps[64][64];     //  8192
  __shared__ __align__(16) u16 RKs[128][64];   // 16384
  __shared__ __align__(16) u16 RQs[128][64];   // 16384
  __shared__ __align__(16) u16 Ts[64][128];    // 16384
  __shared__ __align__(16) u16 Us[64][128];    // 16384

  // XCD swizzle: 8 XCDs, 128 consecutive blocks each
  const int bx = ((blockIdx.x & 7) << 7) | (blockIdx.x >> 3);
  const int it = bx & 15, bn = bx >> 4;
  const int b = bn >> 4, n = bn & 15;
  const int i0 = it * 64;
  const int tid = threadIdx.x, w = tid >> 6, lane = tid & 63;
  const int lj = lane & 15, lg = lane >> 4;

  const u16* qh = qg + (size_t)bn * 65536;
  const u16* kh = kg + (size_t)bn * 65536;
  const u16* vth = vtg + (size_t)bn * 65536;
  const u16* rkh = rkg + (size_t)n * 65600;
  const u16* rqh = rqg + (size_t)n * 65600;
  const float* mk = mask + (size_t)b * 1024;

  // ---- GLL16 staging setup: lane l writes LDS slot base+l*16B (linear);
  // slot (row, gslot) holds logical granule g = gslot ^ (row&7)  (SWZ-consistent).
  const int l8 = lane >> 3, gK = (lane & 7) ^ l8;
  const u16* kb0  = kh  + (size_t)((w * 2 + 0) * 8 + l8) * 64 + gK * 8;
  const u16* kb1  = kh  + (size_t)((w * 2 + 1) * 8 + l8) * 64 + gK * 8;
  const u16* rkb0 = rkh + (size_t)((w * 4 + 0) * 8 + l8) * 64 + gK * 8;
  const u16* rkb1 = rkh + (size_t)((w * 4 + 1) * 8 + l8) * 64 + gK * 8;
  const u16* rkb2 = rkh + (size_t)((w * 4 + 2) * 8 + l8) * 64 + gK * 8;
  const u16* rkb3 = rkh + (size_t)((w * 4 + 3) * 8 + l8) * 64 + gK * 8;
  const u16* rqb0 = rqh + (size_t)((w * 4 + 0) * 8 + l8) * 64 + gK * 8;
  const u16* rqb1 = rqh + (size_t)((w * 4 + 1) * 8 + l8) * 64 + gK * 8;
  const u16* rqb2 = rqh + (size_t)((w * 4 + 2) * 8 + l8) * 64 + gK * 8;
  const u16* rqb3 = rqh + (size_t)((w * 4 + 3) * 8 + l8) * 64 + gK * 8;
  u16* ksd0 = &Ks[0][0]  + (w * 2 + 0) * 512;
  u16* ksd1 = &Ks[0][0]  + (w * 2 + 1) * 512;
  u16* rkd0 = &RKs[0][0] + (w * 4 + 0) * 512;
  u16* rkd1 = &RKs[0][0] + (w * 4 + 1) * 512;
  u16* rkd2 = &RKs[0][0] + (w * 4 + 2) * 512;
  u16* rkd3 = &RKs[0][0] + (w * 4 + 3) * 512;
  u16* rqd0 = &RQs[0][0] + (w * 4 + 0) * 512;
  u16* rqd1 = &RQs[0][0] + (w * 4 + 1) * 512;
  u16* rqd2 = &RQs[0][0] + (w * 4 + 2) * 512;
  u16* rqd3 = &RQs[0][0] + (w * 4 + 3) * 512;

#define STAGE_TILE(J0N) do { \
    const int ddn_ = i0 - (J0N) + 512; \
    int w0n_ = ddn_ - 63; w0n_ = w0n_ < 0 ? 0 : (w0n_ > 897 ? 897 : w0n_); \
    int w0qn_ = (1024 - ddn_) - 63; w0qn_ = w0qn_ < 0 ? 0 : (w0qn_ > 897 ? 897 : w0qn_); \
    GLL16(kb0 + (size_t)(J0N) * 64, ksd0); \
    GLL16(kb1 + (size_t)(J0N) * 64, ksd1); \
    GLL16(rkb0 + (size_t)w0n_ * 64, rkd0); \
    GLL16(rkb1 + (size_t)w0n_ * 64, rkd1); \
    GLL16(rkb2 + (size_t)w0n_ * 64, rkd2); \
    GLL16(rkb3 + (size_t)w0n_ * 64, rkd3); \
    GLL16(rqb0 + (size_t)w0qn_ * 64, rqd0); \
    GLL16(rqb1 + (size_t)w0qn_ * 64, rqd1); \
    GLL16(rqb2 + (size_t)w0qn_ * 64, rqd2); \
    GLL16(rqb3 + (size_t)w0qn_ * 64, rqd3); \
  } while (0)

  // Q fragment -> registers (wave-private rows, constant over jt)
  bf16x8 aq[2];
  #pragma unroll
  for (int k2 = 0; k2 < 2; ++k2)
    aq[k2] = *(const bf16x8*)(qh + (size_t)(i0 + w * 16 + lj) * 64 + k2 * 32 + lg * 8);

  // V row-base pointers (per-lane, advance by j0 per jt)
  const u16* vrow[4];
  #pragma unroll
  for (int d = 0; d < 4; ++d)
    vrow[d] = vth + (size_t)(d * 16 + lj) * 1024 + lg * 8;

  // per-lane constants
  const int swlj = (lj & 7) << 3;             // swizzle for rows ≡ lj (mod 16)
  u16* tsrow = &Ts[w * 16 + lj][0];           // transposed-production write rows
  u16* usrow = &Us[w * 16 + lj][0];
  int baseT[4], swi[4], baseP[4];
  #pragma unroll
  for (int r = 0; r < 4; ++r) {
    const int il = w * 16 + lg * 4 + r;
    baseT[r] = il * 128;
    swi[r] = (il & 7) << 3;
    baseP[r] = il * 64;
  }
  const u16* Ts_f = &Ts[0][0];
  const u16* Us_f = &Us[0][0];
  u16* Ps_f = &Ps[0][0];

  float lsum[4] = {0.f, 0.f, 0.f, 0.f};
  f32x4 accO[4] = {};

  STAGE_TILE(0);  // prologue

  for (int jt = 0; jt < 16; ++jt) {
    const int j0 = jt * 64;
    const int dd = i0 - j0 + 512;
    int w0 = dd - 63; w0 = w0 < 0 ? 0 : (w0 > 897 ? 897 : w0);
    int w0q = (1024 - dd) - 63; w0q = w0q < 0 ? 0 : (w0q > 897 ? 897 : w0q);

    __syncthreads();  // staged K/RK/RQ visible

    bf16x8 ak[2];
    #pragma unroll
    for (int k2 = 0; k2 < 2; ++k2) {
      const int kr = w * 16 + lj;
      ak[k2] = *(const bf16x8*)(&Ks[kr][SWZ(kr, k2 * 32 + lg * 8)]);
    }
    __builtin_amdgcn_s_setprio(1);
    // c2c
    f32x4 scc[4];
    #pragma unroll
    for (int jf = 0; jf < 4; ++jf) {
      scc[jf] = (f32x4){0.f, 0.f, 0.f, 0.f};
      #pragma unroll
      for (int k2 = 0; k2 < 2; ++k2) {
        const int kr = jf * 16 + lj;
        bf16x8 bk8 = *(const bf16x8*)(&Ks[kr][SWZ(kr, k2 * 32 + lg * 8)]);
        scc[jf] = MFMA16(aq[k2], bk8, scc[jf]);
      }
    }
    // Transposed production: T^T = mfma(RK, Q), U^T = mfma(RQ, K).
    // Lane holds 4 consecutive t-cols of row (w*16+lj) -> packed b64 write.
    #pragma unroll
    for (int tf = 0; tf < 8; ++tf) {
      f32x4 t_ = {0.f, 0.f, 0.f, 0.f};
      f32x4 u_ = {0.f, 0.f, 0.f, 0.f};
      #pragma unroll
      for (int k2 = 0; k2 < 2; ++k2) {
        const int rr = tf * 16 + lj;
        bf16x8 brk = *(const bf16x8*)(&RKs[rr][SWZ(rr, k2 * 32 + lg * 8)]);
        bf16x8 brq = *(const bf16x8*)(&RQs[rr][SWZ(rr, k2 * 32 + lg * 8)]);
        t_ = MFMA16(brk, aq[k2], t_);
        u_ = MFMA16(brq, ak[k2], u_);
      }
      uint2 tp, up;
      tp.x = pk2bf(t_[0], t_[1]); tp.y = pk2bf(t_[2], t_[3]);
      up.x = pk2bf(u_[0], u_[1]); up.y = pk2bf(u_[2], u_[3]);
      const int cb = (tf * 16 + lg * 4) ^ swlj;
      *(uint2*)(tsrow + cb) = tp;
      *(uint2*)(usrow + cb) = up;
    }
    __builtin_amdgcn_s_setprio(0);
    __syncthreads();  // T/U visible; K/RK/RQ fully consumed

    if (jt < 15) STAGE_TILE(j0 + 64);  // next tile: latency hides under softmax+PV

    // V tile -> registers (latency hides under softmax)
    bf16x8 vreg[8];
    #pragma unroll
    for (int jk = 0; jk < 2; ++jk)
      #pragma unroll
      for (int d = 0; d < 4; ++d)
        vreg[jk * 4 + d] = *(const bf16x8*)(vrow[d] + j0 + jk * 32);

    // scores + fixed-shift softmax via exp2: p = 2^(sum*SCALE_L2E + (mask-8)*L2E)
    const int E = dd + w * 16 + lg * 4 - lj;  // x1 = clip(E + r - jf*16, 0, 1024)
    const int C2 = 1024 - w0q;
    float mjs[4];
    #pragma unroll
    for (int jf = 0; jf < 4; ++jf)
      mjs[jf] = fmaf(mk[j0 + jf * 16 + lj], LOG2E, M8L2E);
    if (dd >= 63 && dd <= 961) {
      // interior tile: x1 never clips
      #pragma unroll
      for (int jf = 0; jf < 4; ++jf) {
        const int ubase = (jf * 16 + lj) * 128;
        #pragma unroll
        for (int r = 0; r < 4; ++r) {
          const int x1 = E + r - jf * 16;
          const float tT = bf2f(Ts_f[baseT[r] + ((x1 - w0) ^ swi[r])]);
          const float tU = bf2f(Us_f[ubase + ((C2 - x1) ^ swlj)]);
          const float p = __builtin_amdgcn_exp2f(
              fmaf(scc[jf][r] + tT + tU, SCALE_L2E, mjs[jf]));
          lsum[r] += p;
          Ps_f[baseP[r] + ((jf * 16 + lj) ^ (swi[r] & 56))] = f2bf(p);
        }
      }
    } else {
      #pragma unroll
      for (int jf = 0; jf < 4; ++jf) {
        const int ubase = (jf * 16 + lj) * 128;
        #pragma unroll
        for (int r = 0; r < 4; ++r) {
          int x1 = E + r - jf * 16;
          x1 = x1 < 0 ? 0 : (x1 > 1024 ? 1024 : x1);
          const float tT = bf2f(Ts_f[baseT[r] + ((x1 - w0) ^ swi[r])]);
          const float tU = bf2f(Us_f[ubase + ((C2 - x1) ^ swlj)]);
          const float p = __builtin_amdgcn_exp2f(
              fmaf(scc[jf][r] + tT + tU, SCALE_L2E, mjs[jf]));
          lsum[r] += p;
          Ps_f[baseP[r] + ((jf * 16 + lj) ^ (swi[r] & 56))] = f2bf(p);
        }
      }
    }
    // PV: O[i,d] += P[i,j] * V[j,d]  (P rows wave-private; V in registers)
    __builtin_amdgcn_s_setprio(1);
    #pragma unroll
    for (int jk = 0; jk < 2; ++jk) {
      const int pr = w * 16 + lj;
      bf16x8 ap = *(const bf16x8*)(&Ps[pr][SWZ(pr, jk * 32 + lg * 8)]);
      #pragma unroll
      for (int d = 0; d < 4; ++d)
        accO[d] = MFMA16(ap, vreg[jk * 4 + d], accO[d]);
    }
    __builtin_amdgcn_s_setprio(0);
  }

  // final row-sum reduce (j is distributed over the 16 lj lanes)
  #pragma unroll
  for (int off = 1; off < 16; off <<= 1)
    #pragma unroll
    for (int r = 0; r < 4; ++r)
      lsum[r] += __shfl_xor(lsum[r], off);

  #pragma unroll
  for (int r = 0; r < 4; ++r) {
    const float inv = 1.f / lsum[r];
    const int i = i0 + w * 16 + lg * 4 + r;
    #pragma unroll
    for (int d = 0; d < 4; ++d)
      out[((size_t)b * 1024 + i) * 1024 + n * 64 + d * 16 + lj] = accO[d][r] * inv;
  }
#undef STAGE_TILE
}

extern "C" void kernel_launch(void* const* d_in, const int* in_sizes, int n_in,
                              void* d_out, int out_size, void* d_ws, size_t ws_size,
                              hipStream_t stream) {
  const float* hs   = (const float*)d_in[0];
  const float* mask = (const float*)d_in[1];
  const float* rel  = (const float*)d_in[2];
  const float* Wq   = (const float*)d_in[3];
  const float* bq   = (const float*)d_in[4];
  const float* Wk   = (const float*)d_in[5];
  const float* bk   = (const float*)d_in[6];
  const float* Wv   = (const float*)d_in[7];
  const float* bv   = (const float*)d_in[8];
  const float* Wpk  = (const float*)d_in[9];
  const float* bpk  = (const float*)d_in[10];
  const float* Wpq  = (const float*)d_in[11];
  const float* bpq  = (const float*)d_in[12];
  float* outp = (float*)d_out;

  u16* p = (u16*)d_ws;
  u16* hsb  = p; p += (size_t)4096 * 1024;
  u16* relb = p; p += (size_t)1025 * 1024;
  u16* WqT  = p; p += (size_t)1024 * 1024;   // WqT/WkT/WvT consecutive
  u16* WkT  = p; p += (size_t)1024 * 1024;
  u16* WvT  = p; p += (size_t)1024 * 1024;
  u16* WpkT = p; p += (size_t)1024 * 1024;   // WpkT/WpqT consecutive
  u16* WpqT = p; p += (size_t)1024 * 1024;
  u16* qws  = p; p += (size_t)4096 * 1024;   // q/k/v consecutive
  u16* kws  = p; p += (size_t)4096 * 1024;
  u16* vws  = p; p += (size_t)4096 * 1024;
  u16* rkws = p; p += (size_t)16 * 1025 * 64;  // rk/rq consecutive
  u16* rqws = p; p += (size_t)16 * 1025 * 64;
  if ((size_t)((char*)p - (char*)d_ws) > ws_size) return;  // ws too small: bail
  (void)kws; (void)rqws;

  cvt_bf16<<<4096, 256, 0, stream>>>(hs, hsb, 1048576);
  cvt_bf16<<<1025, 256, 0, stream>>>(rel, relb, 262400);
  transp5_bf16<<<dim3(32, 32, 5), 256, 0, stream>>>(Wq, Wk, Wv, Wpk, Wpq,
                                                    WqT, WkT, WvT, WpkT, WpqT);

  gemm_multi<<<dim3(32, 24), 256, 0, stream>>>(hsb, WqT, bq, bk, bv, qws, 4096, 0);
  gemm_multi<<<dim3(9, 16),  256, 0, stream>>>(relb, WpkT, bpk, bpq, bpq, rkws, 1025, 1);

  attn_fused<<<1024, 256, 0, stream>>>(qws, kws, vws, rkws, rqws, mask, outp);
}